// Round 4
// baseline (4654.623 us; speedup 1.0000x reference)
//
#include <hip/hip_runtime.h>

#define NNODES 50000
#define NEDGES 800000
#define HDIM 128
#define DOUT 64
#define NLAYERS 3
#define NEG_SLOPE 0.2f

#define NODE_OUT_ELEMS (NNODES * DOUT)             // 3,200,000
#define EDGE_OUT_ELEMS (NEDGES * 3)                // 2,400,000
#define GEMB_OFF (NODE_OUT_ELEMS + EDGE_OUT_ELEMS) // 5,600,000

typedef __attribute__((ext_vector_type(8))) short short8;
typedef __attribute__((ext_vector_type(4))) float f32x4;

__device__ __forceinline__ float bf2f(unsigned short u) {
    union { unsigned int i; float f; } v; v.i = ((unsigned int)u) << 16; return v.f;
}
__device__ __forceinline__ unsigned short f2bf(float f) {
    union { unsigned int i; float f; } v; v.f = f;
    unsigned int b = v.i;
    unsigned int r = (b + 0x7FFFu + ((b >> 16) & 1u)) >> 16;
    return (unsigned short)r;
}
__device__ __forceinline__ float leaky(float x) { return x > 0.f ? x : NEG_SLOPE * x; }

// Edge fetch: which=0 -> src, which=1 -> dst. iflag=1 -> int32, 0 -> int64.
__device__ __forceinline__ int eget(const int* e32, const int* iflag, int which, int e) {
    int idx = which * NEDGES + e;
    return (*iflag) ? e32[idx] : e32[2 * idx];
}

__global__ void zero_int_kernel(int* p, int n) {
    int i = blockIdx.x * 256 + threadIdx.x;
    if (i < n) p[i] = 0;
}
__global__ void zero_f32_kernel(float* p, int n) {
    int i = blockIdx.x * 256 + threadIdx.x;
    if (i < n) p[i] = 0.f;
}

__global__ void detect_f32_kernel(const unsigned short* xb, int* flag) {
    int hit = 0;
    for (int j = threadIdx.x; j < 4096; j += 256) {
        int e = (xb[j] >> 7) & 0xFF;
        if (e >= 0x90) hit = 1;
    }
    if (hit) atomicOr(flag, 1);
}
// Sampled int64 detection (one block): for int64 input every odd int32 is a
// zero high-word; for int32 input odd positions hold node indices. 16384
// strided samples decide with certainty on this data; <=4 atomics total.
__global__ void detect_i64_kernel(const int* e32, int* flag) {
    int hit = 0;
    for (int t = threadIdx.x; t < 16384; t += 256) {
        int i = t * 48;                       // 16383*48 = 786384 < NEDGES
        if (e32[2 * i + 1] != 0) hit = 1;
    }
    if (__any(hit)) {
        if ((threadIdx.x & 63) == 0) atomicOr(flag, 1);
    }
}

__global__ void cvt_kernel(const void* src, float* dst, int n, const int* f32flag) {
    int i = blockIdx.x * 256 + threadIdx.x;
    if (i < n)
        dst[i] = (*f32flag) ? ((const float*)src)[i]
                            : bf2f(((const unsigned short*)src)[i]);
}
__global__ void cvt_layerW_kernel(const void* gat_W, float* dst, int l,
                                  const int* f32flag) {
    int i = blockIdx.x * 256 + threadIdx.x;
    if (i < HDIM * HDIM) {
        size_t idx = (size_t)l * HDIM * HDIM + i;
        dst[i] = (*f32flag) ? ((const float*)gat_W)[idx]
                            : bf2f(((const unsigned short*)gat_W)[idx]);
    }
}

// ---------------------------------------------------------------------------
// MFMA GEMM: C[M,N] = op(A[M,128] @ B[128,N] + bias), N in {128, 64}.
// MFMA path (inputs bf16): A read as bf16, B recovered exactly to bf16 from
// the f32 cvt array (values are bf16-originated), f32 accumulate -> same
// precision as the scalar f32 kernel, only summation order differs.
// Fallback path (*f32flag): scalar f32 loop; A staged to LDS when !a_dyn so
// the in-place (C==A) call stays race-free.
// 256 threads = 4 waves; 64 rows/block; wave covers 64 rows x N/4 cols.
// ---------------------------------------------------------------------------
__global__ __launch_bounds__(256) void gemm_mfma_kernel(
    const void* Av, int a_dyn, const float* __restrict__ Bf,
    const float* __restrict__ bias, void* Cv, int out_f32,
    int M, int N, int relu, const int* __restrict__ f32flag)
{
    constexpr int KP = 128 + 8;
    __shared__ unsigned short sA[64 * KP];        // 17,408 B
    const int f32 = *f32flag;
    const int tid = threadIdx.x;
    const int row0 = blockIdx.x * 64;

    if (!f32) {
        const unsigned short* A = (const unsigned short*)Av;
        for (int c = tid; c < 64 * 16; c += 256) {
            int r = c >> 4, cp = c & 15;
            int gr = row0 + r;
            uint4 v = {0u, 0u, 0u, 0u};
            if (gr < M) v = *(const uint4*)(A + (size_t)gr * 128 + cp * 8);
            *(uint4*)(&sA[r * KP + cp * 8]) = v;
        }
        __syncthreads();

        const int wave = tid >> 6, lane = tid & 63;
        const int quad = lane >> 4, l15 = lane & 15;
        const int ntc = N >> 6;                   // 128 -> 2, 64 -> 1
        const int ncol0 = wave * (ntc * 16);

        short8 bw[4][2];
        for (int kk = 0; kk < 4; kk++)
            for (int nt = 0; nt < ntc; nt++) {
                int n = ncol0 + nt * 16 + l15;
                short8 t;
                #pragma unroll
                for (int j = 0; j < 8; j++)
                    t[j] = (short)f2bf(Bf[(size_t)(kk * 32 + quad * 8 + j) * N + n]);
                bw[kk][nt] = t;
            }

        float bv[2] = {0.f, 0.f};
        if (bias)
            for (int nt = 0; nt < ntc; nt++) bv[nt] = bias[ncol0 + nt * 16 + l15];

        f32x4 acc[4][2];
        for (int mt = 0; mt < 4; mt++)
            for (int nt = 0; nt < ntc; nt++) {
                acc[mt][nt][0] = bv[nt]; acc[mt][nt][1] = bv[nt];
                acc[mt][nt][2] = bv[nt]; acc[mt][nt][3] = bv[nt];
            }

        #pragma unroll
        for (int kk = 0; kk < 4; kk++) {
            short8 a[4];
            #pragma unroll
            for (int mt = 0; mt < 4; mt++)
                a[mt] = *(const short8*)(&sA[(mt * 16 + l15) * KP + kk * 32 + quad * 8]);
            #pragma unroll
            for (int mt = 0; mt < 4; mt++)
                for (int nt = 0; nt < ntc; nt++)
                    acc[mt][nt] = __builtin_amdgcn_mfma_f32_16x16x32_bf16(
                        a[mt], bw[kk][nt], acc[mt][nt], 0, 0, 0);
        }

        for (int mt = 0; mt < 4; mt++)
            for (int nt = 0; nt < ntc; nt++)
                #pragma unroll
                for (int q = 0; q < 4; q++) {
                    int row = row0 + mt * 16 + quad * 4 + q;
                    if (row < M) {
                        int coln = ncol0 + nt * 16 + l15;
                        float v = acc[mt][nt][q];
                        if (relu) v = fmaxf(v, 0.f);
                        if (out_f32) ((float*)Cv)[(size_t)row * N + coln] = v;
                        else ((unsigned short*)Cv)[(size_t)row * N + coln] = f2bf(v);
                    }
                }
    } else {
        // ---- scalar f32 fallback ----
        if (!a_dyn) {
            const unsigned short* A = (const unsigned short*)Av;
            for (int c = tid; c < 64 * 16; c += 256) {
                int r = c >> 4, cp = c & 15;
                int gr = row0 + r;
                uint4 v = {0u, 0u, 0u, 0u};
                if (gr < M) v = *(const uint4*)(A + (size_t)gr * 128 + cp * 8);
                *(uint4*)(&sA[r * KP + cp * 8]) = v;
            }
            __syncthreads();
        }
        const int col = tid % N;
        const int nrg = 256 / N;                  // 2 or 4
        const int rg = tid / N;
        const int rpr = 64 / nrg;                 // 32 or 16
        for (int r8 = 0; r8 < rpr; r8++) {
            int lr = rg * rpr + r8;
            int row = row0 + lr;
            if (row >= M) continue;
            float acc = bias ? bias[col] : 0.f;
            for (int k = 0; k < 128; k++) {
                float a = a_dyn ? ((const float*)Av)[(size_t)row * 128 + k]
                                : bf2f(sA[lr * KP + k]);
                acc += a * Bf[(size_t)k * N + col];
            }
            if (relu) acc = fmaxf(acc, 0.f);
            if (out_f32) ((float*)Cv)[(size_t)row * N + col] = acc;
            else ((unsigned short*)Cv)[(size_t)row * N + col] = f2bf(acc);
        }
    }
}

__global__ void alpha_kernel(const unsigned short* xw,
                             const float* a_s, const float* a_d,
                             float* alpha_s, float* alpha_d) {
    int wave = threadIdx.x >> 6, lane = threadIdx.x & 63;
    int n = blockIdx.x * 4 + wave;
    if (n >= NNODES) return;
    float v0 = bf2f(xw[(size_t)n * HDIM + lane]);
    float v1 = bf2f(xw[(size_t)n * HDIM + 64 + lane]);
    float ds = v0 * a_s[lane] + v1 * a_s[64 + lane];
    float dd = v0 * a_d[lane] + v1 * a_d[64 + lane];
    for (int d = 32; d >= 1; d >>= 1) { ds += __shfl_xor(ds, d); dd += __shfl_xor(dd, d); }
    if (lane == 0) { alpha_s[n] = ds; alpha_d[n] = dd; }
}

// ---- CSR build (group edges by dst) ----
__global__ void count_kernel(const int* e32, const int* iflag, int* cnt) {
    int e = blockIdx.x * 256 + threadIdx.x;
    if (e < NEDGES) atomicAdd(&cnt[eget(e32, iflag, 1, e)], 1);
}
__global__ void scan1_kernel(const int* cnt, int* off, int* bsum) {
    __shared__ int s[256];
    int t = threadIdx.x, i = blockIdx.x * 256 + t;
    int v = (i < NNODES) ? cnt[i] : 0;
    s[t] = v;
    __syncthreads();
    for (int d = 1; d < 256; d <<= 1) {
        int add = (t >= d) ? s[t - d] : 0;
        __syncthreads();
        s[t] += add;
        __syncthreads();
    }
    if (i < NNODES) off[i] = s[t] - v;          // exclusive
    if (t == 255) bsum[blockIdx.x] = s[255];
}
__global__ void scan2_kernel(int* bsum, int nblk) {
    if (threadIdx.x == 0 && blockIdx.x == 0) {
        int run = 0;
        for (int c = 0; c < nblk; c++) { int t = bsum[c]; bsum[c] = run; run += t; }
    }
}
__global__ void scan3_kernel(int* off, const int* bsum) {
    int i = blockIdx.x * 256 + threadIdx.x;
    if (i < NNODES) off[i] += bsum[blockIdx.x];
}
__global__ void fill_kernel(const int* e32, const int* iflag, const int* off,
                            int* cur, int* csr_src, int* csr_dst, int* csr_eid,
                            int use_csr) {
    int e = blockIdx.x * 256 + threadIdx.x;
    if (e < NEDGES) {
        int sidx = eget(e32, iflag, 0, e);
        int d = eget(e32, iflag, 1, e);
        int p = atomicAdd(&cur[d], 1);
        int pos = off[d] + p;
        csr_src[pos] = sidx;
        if (use_csr) {
            csr_dst[pos] = d;
            csr_eid[pos] = e;
        }
    }
}

// GAT aggregation: one wave per node; h = relu(h + agg + b) in place.
// 64 lanes = 4 edge-slots x 16 feature-lanes; idx+alpha prefetched and
// shfl-broadcast so only the xw row gather remains in the hot loop.
__global__ void aggregate_kernel(const unsigned short* __restrict__ xw,
                                 const float* __restrict__ as_, const float* __restrict__ ad_,
                                 const int* __restrict__ off, const int* __restrict__ csr_src,
                                 const float* __restrict__ gat_b, unsigned short* __restrict__ h) {
    int wave = threadIdx.x >> 6, lane = threadIdx.x & 63;
    int n = blockIdx.x * 4 + wave;
    if (n >= NNODES) return;
    int o0 = off[n];
    int o1 = (n == NNODES - 1) ? NEDGES : off[n + 1];
    int deg = o1 - o0;
    float adn = ad_[n];
    float lself = leaky(as_[n] + adn);

    int deg64 = deg < 64 ? deg : 64;
    int idxv = 0; float av = 0.f;
    if (lane < deg64) { idxv = csr_src[o0 + lane]; av = as_[idxv]; }

    float m = lself;
    if (lane < deg64) m = fmaxf(m, leaky(av + adn));
    for (int i = 64 + lane; i < deg; i += 64) {
        int s = csr_src[o0 + i];
        m = fmaxf(m, leaky(as_[s] + adn));
    }
    #pragma unroll
    for (int d = 32; d >= 1; d >>= 1) m = fmaxf(m, __shfl_xor(m, d));

    const int slot = lane >> 4;
    const int l15  = lane & 15;
    float denom = 0.f;
    float acc[8];
    #pragma unroll
    for (int k = 0; k < 8; k++) acc[k] = 0.f;

    for (int t0 = 0; t0 < deg64; t0 += 4) {
        int i = t0 + slot;
        int sidx   = __shfl(idxv, i);
        float aval = __shfl(av, i);
        if (i < deg64) {
            float p = __expf(leaky(aval + adn) - m);
            denom += p;
            uint4 rv = *(const uint4*)(xw + (size_t)sidx * HDIM + l15 * 8);
            const unsigned short* rp = (const unsigned short*)&rv;
            #pragma unroll
            for (int k = 0; k < 8; k++) acc[k] += p * bf2f(rp[k]);
        }
    }
    for (int i = 64 + slot; i < deg; i += 4) {
        int s = csr_src[o0 + i];
        float p = __expf(leaky(as_[s] + adn) - m);
        denom += p;
        uint4 rv = *(const uint4*)(xw + (size_t)s * HDIM + l15 * 8);
        const unsigned short* rp = (const unsigned short*)&rv;
        #pragma unroll
        for (int k = 0; k < 8; k++) acc[k] += p * bf2f(rp[k]);
    }

    #pragma unroll
    for (int d = 16; d <= 32; d <<= 1) {
        denom += __shfl_xor(denom, d);
        #pragma unroll
        for (int k = 0; k < 8; k++) acc[k] += __shfl_xor(acc[k], d);
    }

    float ps = __expf(lself - m);
    denom += ps;
    uint4 sv = *(const uint4*)(xw + (size_t)n * HDIM + l15 * 8);
    const unsigned short* sp = (const unsigned short*)&sv;
    #pragma unroll
    for (int k = 0; k < 8; k++) acc[k] += ps * bf2f(sp[k]);

    if (slot == 0) {
        float inv = 1.f / denom;
        size_t base = (size_t)n * HDIM + l15 * 8;
        uint4 hv = *(const uint4*)(h + base);
        const unsigned short* hp = (const unsigned short*)&hv;
        unsigned short outv[8];
        #pragma unroll
        for (int k = 0; k < 8; k++) {
            float hx = bf2f(hp[k]);
            float bx = gat_b[l15 * 8 + k];
            outv[k] = f2bf(fmaxf(hx + acc[k] * inv + bx, 0.f));
        }
        *(uint4*)(h + base) = *(uint4*)outv;
    }
}

// ---------------------------------------------------------------------------
// Edge MLP via algebraic split (A = h@We1_top + be1, B = h@We1_bot per node):
// per edge v = relu(A[src]+B[dst]); out = v @ We2 + be2. Barrier-free.
// ---------------------------------------------------------------------------
__global__ __launch_bounds__(256) void edge_split_kernel(
    const unsigned short* __restrict__ A, const unsigned short* __restrict__ B,
    const int* __restrict__ e32, const int* __restrict__ iflag,
    const int* __restrict__ csr_src, const int* __restrict__ csr_dst,
    const int* __restrict__ csr_eid, int use_csr,
    const float* __restrict__ We2, const float* __restrict__ be2,
    float* __restrict__ eout)
{
    const int lane = threadIdx.x & 63;
    const int slot = lane >> 4, l15 = lane & 15;

    float w2[8][3];
    #pragma unroll
    for (int j = 0; j < 8; j++)
        #pragma unroll
        for (int c = 0; c < 3; c++)
            w2[j][c] = We2[(l15 * 8 + j) * 3 + c];
    const float bo0 = be2[0], bo1 = be2[1], bo2 = be2[2];

    const int gw = (blockIdx.x * 256 + threadIdx.x) >> 6;
    const int stride = gridDim.x * 16;
    for (int e = gw * 4 + slot; e < NEDGES; e += stride) {
        int s, d, oe;
        if (use_csr) { s = csr_src[e]; d = csr_dst[e]; oe = csr_eid[e]; }
        else {
            s = eget(e32, iflag, 0, e);
            d = eget(e32, iflag, 1, e);
            oe = e;
        }
        uint4 avv = *(const uint4*)(A + (size_t)s * HDIM + l15 * 8);
        uint4 bvv = *(const uint4*)(B + (size_t)d * HDIM + l15 * 8);
        const unsigned short* ap = (const unsigned short*)&avv;
        const unsigned short* bp = (const unsigned short*)&bvv;
        float s0 = 0.f, s1 = 0.f, s2 = 0.f;
        #pragma unroll
        for (int j = 0; j < 8; j++) {
            float v = fmaxf(bf2f(ap[j]) + bf2f(bp[j]), 0.f);
            s0 += v * w2[j][0]; s1 += v * w2[j][1]; s2 += v * w2[j][2];
        }
        #pragma unroll
        for (int dd = 1; dd < 16; dd <<= 1) {
            s0 += __shfl_xor(s0, dd);
            s1 += __shfl_xor(s1, dd);
            s2 += __shfl_xor(s2, dd);
        }
        if (l15 == 0) {
            eout[(size_t)oe * 3 + 0] = s0 + bo0;
            eout[(size_t)oe * 3 + 1] = s1 + bo1;
            eout[(size_t)oe * 3 + 2] = s2 + bo2;
        }
    }
}

__global__ void gsum_kernel(const unsigned short* h, float* gsum) {
    int f = threadIdx.x;
    float local = 0.f;
    int n0 = blockIdx.x * 200;
    for (int j = 0; j < 200; j++) local += bf2f(h[(size_t)(n0 + j) * HDIM + f]);
    atomicAdd(&gsum[f], local);
}
__global__ void gout_kernel(const float* gsum, float* out) {
    int f = threadIdx.x;
    out[GEMB_OFF + f] = gsum[f] * (1.f / (float)NNODES);
}

extern "C" __attribute__((visibility("default")))
void kernel_launch(void* const* d_in, const int* in_sizes, int n_in,
                   void* d_out, int out_size, void* d_ws, size_t ws_size,
                   hipStream_t stream) {
    const void* x      = d_in[0];
    const int*  eidx   = (const int*)d_in[1];
    const void* W_emb  = d_in[2];
    const void* b_emb  = d_in[3];
    const void* gat_W  = d_in[4];
    const void* gat_as = d_in[5];
    const void* gat_ad = d_in[6];
    const void* gat_b  = d_in[7];
    const void* Wn1    = d_in[8];
    const void* bn1    = d_in[9];
    const void* Wn2    = d_in[10];
    const void* bn2    = d_in[11];
    const void* We1    = d_in[12];
    const void* be1    = d_in[13];
    const void* We2    = d_in[14];
    const void* be2    = d_in[15];
    float* out = (float*)d_out;   // output dtype: float32

    char* ws = (char*)d_ws;
    unsigned short* h       = (unsigned short*)(ws);                // 12.8 MB
    unsigned short* xw      = (unsigned short*)(ws + 12800000);     // 12.8 MB
    float*          alpha_s = (float*)(ws + 25600000);              // 200 KB
    float*          alpha_d = (float*)(ws + 25800000);              // 200 KB
    int*            cnt     = (int*)(ws + 26000000);                // 200 KB
    int*            off     = (int*)(ws + 26200000);                // 200 KB
    int*            bsum    = (int*)(ws + 26400000);                // 1 KB
    float*          gsum    = (float*)(ws + 26401024);              // 512 B
    int*            iflag   = (int*)(ws + 26401536);
    int*            fflag   = (int*)(ws + 26401540);
    float*          We1c    = (float*)(ws + 26402048);              // 128 KB
    float*          We2c    = (float*)(ws + 26533120);
    float*          asc     = (float*)(ws + 26534656);
    float*          adc     = (float*)(ws + 26536192);
    float*          gbc     = (float*)(ws + 26537728);
    float*          bembc   = (float*)(ws + 26539264);
    float*          bn1c    = (float*)(ws + 26539776);
    float*          bn2c    = (float*)(ws + 26540288);
    float*          be1c    = (float*)(ws + 26540544);
    float*          be2c    = (float*)(ws + 26541056);
    float*          Wlc     = (float*)(ws + 26542080);              // 64 KB
    int*            csr_src = (int*)(ws + 26608000);                // 3.2 MB -> 29.81 MB
    int*            csr_dst = (int*)(ws + 29808000);                // 3.2 MB (optional)
    int*            csr_eid = (int*)(ws + 33008000);                // 3.2 MB -> 36.21 MB (optional)

    // Temporal-reuse aliases (zero extra footprint):
    // Wembc lives in the 'off' region: consumed by the embedding GEMM, which
    // completes before scan1 writes 'off'.
    float* Wembc = (float*)(ws + 26200000);        // 64 KB <= off region (200 KB)
    // Wn1c/Wn2c live in the 'cnt' region: written after fill_kernel (last use
    // of cnt), consumed by the node MLP.
    float* Wn1c = (float*)(ws + 26000000);         // 64 KB
    float* Wn2c = (float*)(ws + 26065536);         // 32 KB (ends 26,098,304)

    const int use_csr = (ws_size >= (size_t)36208000) ? 1 : 0;

    const int node_blks = (NNODES + 255) / 256;    // 196
    const int edge_blks = (NEDGES + 255) / 256;    // 3125
    const int g64       = (NNODES + 63) / 64;      // 782

    zero_int_kernel<<<1, 256, 0, stream>>>(iflag, 2);
    zero_int_kernel<<<node_blks, 256, 0, stream>>>(cnt, NNODES);
    zero_f32_kernel<<<1, 256, 0, stream>>>(gsum, HDIM);

    detect_f32_kernel<<<1, 256, 0, stream>>>((const unsigned short*)x, fflag);
    detect_i64_kernel<<<1, 256, 0, stream>>>(eidx, iflag);

    cvt_kernel<<<128, 256, 0, stream>>>(We1, We1c, 256 * 128, fflag);
    cvt_kernel<<<2, 256, 0, stream>>>(We2, We2c, 128 * 3, fflag);
    cvt_kernel<<<2, 256, 0, stream>>>(gat_as, asc, 3 * 128, fflag);
    cvt_kernel<<<2, 256, 0, stream>>>(gat_ad, adc, 3 * 128, fflag);
    cvt_kernel<<<2, 256, 0, stream>>>(gat_b, gbc, 3 * 128, fflag);
    cvt_kernel<<<1, 256, 0, stream>>>(b_emb, bembc, 128, fflag);
    cvt_kernel<<<1, 256, 0, stream>>>(bn1, bn1c, 128, fflag);
    cvt_kernel<<<1, 256, 0, stream>>>(bn2, bn2c, 64, fflag);
    cvt_kernel<<<1, 256, 0, stream>>>(be1, be1c, 128, fflag);
    cvt_kernel<<<1, 256, 0, stream>>>(be2, be2c, 3, fflag);
    cvt_kernel<<<64, 256, 0, stream>>>(W_emb, Wembc, 128 * 128, fflag);

    // h = relu(x @ W_emb + b_emb)   (a_dyn=1: A dtype follows input)
    gemm_mfma_kernel<<<g64, 256, 0, stream>>>(
        x, 1, Wembc, bembc, h, 0, NNODES, 128, 1, fflag);

    // CSR build (once); 'off' region free again only after its last read, but
    // Wembc was consumed by the GEMM above before scan1 writes 'off'.
    count_kernel<<<edge_blks, 256, 0, stream>>>(eidx, iflag, cnt);
    scan1_kernel<<<node_blks, 256, 0, stream>>>(cnt, off, bsum);
    scan2_kernel<<<1, 64, 0, stream>>>(bsum, node_blks);
    scan3_kernel<<<node_blks, 256, 0, stream>>>(off, bsum);
    zero_int_kernel<<<node_blks, 256, 0, stream>>>(cnt, NNODES);
    fill_kernel<<<edge_blks, 256, 0, stream>>>(eidx, iflag, off, cnt,
                                               csr_src, csr_dst, csr_eid, use_csr);

    // cnt region now dead -> stash node-MLP weights there.
    cvt_kernel<<<64, 256, 0, stream>>>(Wn1, Wn1c, 128 * 128, fflag);
    cvt_kernel<<<32, 256, 0, stream>>>(Wn2, Wn2c, 128 * 64, fflag);

    for (int l = 0; l < NLAYERS; l++) {
        cvt_layerW_kernel<<<64, 256, 0, stream>>>(gat_W, Wlc, l, fflag);
        gemm_mfma_kernel<<<g64, 256, 0, stream>>>(
            h, 0, Wlc, (const float*)0, xw, 0, NNODES, 128, 0, fflag);
        alpha_kernel<<<(NNODES + 3) / 4, 256, 0, stream>>>(
            xw, asc + l * HDIM, adc + l * HDIM, alpha_s, alpha_d);
        aggregate_kernel<<<(NNODES + 3) / 4, 256, 0, stream>>>(
            xw, alpha_s, alpha_d, off, csr_src, gbc + l * HDIM, h);
    }

    // node MLP
    gemm_mfma_kernel<<<g64, 256, 0, stream>>>(
        h, 0, Wn1c, bn1c, xw, 0, NNODES, 128, 1, fflag);
    gemm_mfma_kernel<<<g64, 256, 0, stream>>>(
        xw, 0, Wn2c, bn2c, out, 1, NNODES, 64, 0, fflag);

    // graph embedding (must precede the in-place B GEMM that overwrites h)
    gsum_kernel<<<NNODES / 200, 128, 0, stream>>>(h, gsum);
    gout_kernel<<<1, 128, 0, stream>>>(gsum, out);

    // edge MLP via split: A = h@We1_top + be1 -> xw; B = h@We1_bot -> h (in place)
    gemm_mfma_kernel<<<g64, 256, 0, stream>>>(
        h, 0, We1c, be1c, xw, 0, NNODES, 128, 0, fflag);
    gemm_mfma_kernel<<<g64, 256, 0, stream>>>(
        h, 0, We1c + 128 * 128, (const float*)0, h, 0, NNODES, 128, 0, fflag);
    edge_split_kernel<<<2048, 256, 0, stream>>>(
        xw, h, eidx, iflag, csr_src, csr_dst, csr_eid, use_csr,
        We2c, be2c, out + NODE_OUT_ELEMS);
}

// Round 5
// 4540.697 us; speedup vs baseline: 1.0251x; 1.0251x over previous
//
#include <hip/hip_runtime.h>

#define NNODES 50000
#define NEDGES 800000
#define HDIM 128
#define DOUT 64
#define NLAYERS 3
#define NEG_SLOPE 0.2f

#define NODE_OUT_ELEMS (NNODES * DOUT)             // 3,200,000
#define EDGE_OUT_ELEMS (NEDGES * 3)                // 2,400,000
#define GEMB_OFF (NODE_OUT_ELEMS + EDGE_OUT_ELEMS) // 5,600,000

typedef __attribute__((ext_vector_type(8))) short short8;
typedef __attribute__((ext_vector_type(4))) float f32x4;

__device__ __forceinline__ float bf2f(unsigned short u) {
    union { unsigned int i; float f; } v; v.i = ((unsigned int)u) << 16; return v.f;
}
__device__ __forceinline__ unsigned short f2bf(float f) {
    union { unsigned int i; float f; } v; v.f = f;
    unsigned int b = v.i;
    unsigned int r = (b + 0x7FFFu + ((b >> 16) & 1u)) >> 16;
    return (unsigned short)r;
}
__device__ __forceinline__ float leaky(float x) { return x > 0.f ? x : NEG_SLOPE * x; }

// Edge fetch: which=0 -> src, which=1 -> dst. iflag=1 -> int32, 0 -> int64.
__device__ __forceinline__ int eget(const int* e32, const int* iflag, int which, int e) {
    int idx = which * NEDGES + e;
    return (*iflag) ? e32[idx] : e32[2 * idx];
}

__global__ void zero_int_kernel(int* p, int n) {
    int i = blockIdx.x * 256 + threadIdx.x;
    if (i < n) p[i] = 0;
}
__global__ void zero_f32_kernel(float* p, int n) {
    int i = blockIdx.x * 256 + threadIdx.x;
    if (i < n) p[i] = 0.f;
}

__global__ void detect_f32_kernel(const unsigned short* xb, int* flag) {
    int hit = 0;
    for (int j = threadIdx.x; j < 4096; j += 256) {
        int e = (xb[j] >> 7) & 0xFF;
        if (e >= 0x90) hit = 1;
    }
    if (hit) atomicOr(flag, 1);
}
// Sampled int64 detection (one block, <=4 atomics).
__global__ void detect_i64_kernel(const int* e32, int* flag) {
    int hit = 0;
    for (int t = threadIdx.x; t < 16384; t += 256) {
        int i = t * 48;                       // 16383*48 = 786384 < NEDGES
        if (e32[2 * i + 1] != 0) hit = 1;
    }
    if (__any(hit)) {
        if ((threadIdx.x & 63) == 0) atomicOr(flag, 1);
    }
}

__global__ void cvt_kernel(const void* src, float* dst, int n, const int* f32flag) {
    int i = blockIdx.x * 256 + threadIdx.x;
    if (i < n)
        dst[i] = (*f32flag) ? ((const float*)src)[i]
                            : bf2f(((const unsigned short*)src)[i]);
}
__global__ void cvt_layerW_kernel(const void* gat_W, float* dst, int l,
                                  const int* f32flag) {
    int i = blockIdx.x * 256 + threadIdx.x;
    if (i < HDIM * HDIM) {
        size_t idx = (size_t)l * HDIM * HDIM + i;
        dst[i] = (*f32flag) ? ((const float*)gat_W)[idx]
                            : bf2f(((const unsigned short*)gat_W)[idx]);
    }
}

// ---------------------------------------------------------------------------
// GEMM: C[M,N] = op(A[M,128] @ B[128,N] + bias), N in {128, 64}.
// MFMA path: taken whenever A is bf16 (a_dyn=0, i.e. internal workspace; or
// a_dyn=1 with bf16 input). A staged to LDS bf16; B rounded f32->bf16 (RNE)
// at fragment load; f32 accumulate. Fragment layout identical to the
// hardware-validated edge_mlp_mfma of earlier rounds.
// Scalar path: only for a_dyn=1 && f32 input (the embedding GEMM, N=128).
// 4 sub-tiles of 16 rows, 8 accumulators/thread — bit-identical arithmetic
// to the proven round-3 gemm128 f32 branch.
// 256 threads = 4 waves; 64 rows/block.
// ---------------------------------------------------------------------------
__global__ __launch_bounds__(256) void gemm_mfma_kernel(
    const void* Av, int a_dyn, const float* __restrict__ Bf,
    const float* __restrict__ bias, void* Cv, int out_f32,
    int M, int N, int relu, const int* __restrict__ f32flag)
{
    constexpr int KP = 128 + 8;
    __shared__ unsigned short sA[64 * KP];        // 17,408 B (recast for scalar path)
    const int tid = threadIdx.x;
    const int row0 = blockIdx.x * 64;
    const int use_mfma = !(a_dyn && (*f32flag));

    if (use_mfma) {
        const unsigned short* A = (const unsigned short*)Av;
        for (int c = tid; c < 64 * 16; c += 256) {
            int r = c >> 4, cp = c & 15;
            int gr = row0 + r;
            uint4 v = {0u, 0u, 0u, 0u};
            if (gr < M) v = *(const uint4*)(A + (size_t)gr * 128 + cp * 8);
            *(uint4*)(&sA[r * KP + cp * 8]) = v;
        }
        __syncthreads();

        const int wave = tid >> 6, lane = tid & 63;
        const int quad = lane >> 4, l15 = lane & 15;
        const int ntc = N >> 6;                   // 128 -> 2, 64 -> 1
        const int ncol0 = wave * (ntc * 16);

        short8 bw[4][2];
        for (int kk = 0; kk < 4; kk++)
            for (int nt = 0; nt < ntc; nt++) {
                int n = ncol0 + nt * 16 + l15;
                short8 t;
                #pragma unroll
                for (int j = 0; j < 8; j++)
                    t[j] = (short)f2bf(Bf[(size_t)(kk * 32 + quad * 8 + j) * N + n]);
                bw[kk][nt] = t;
            }

        float bv[2] = {0.f, 0.f};
        if (bias)
            for (int nt = 0; nt < ntc; nt++) bv[nt] = bias[ncol0 + nt * 16 + l15];

        f32x4 acc[4][2];
        for (int mt = 0; mt < 4; mt++)
            for (int nt = 0; nt < ntc; nt++) {
                acc[mt][nt][0] = bv[nt]; acc[mt][nt][1] = bv[nt];
                acc[mt][nt][2] = bv[nt]; acc[mt][nt][3] = bv[nt];
            }

        #pragma unroll
        for (int kk = 0; kk < 4; kk++) {
            short8 a[4];
            #pragma unroll
            for (int mt = 0; mt < 4; mt++)
                a[mt] = *(const short8*)(&sA[(mt * 16 + l15) * KP + kk * 32 + quad * 8]);
            #pragma unroll
            for (int mt = 0; mt < 4; mt++)
                for (int nt = 0; nt < ntc; nt++)
                    acc[mt][nt] = __builtin_amdgcn_mfma_f32_16x16x32_bf16(
                        a[mt], bw[kk][nt], acc[mt][nt], 0, 0, 0);
        }

        for (int mt = 0; mt < 4; mt++)
            for (int nt = 0; nt < ntc; nt++)
                #pragma unroll
                for (int q = 0; q < 4; q++) {
                    int row = row0 + mt * 16 + quad * 4 + q;
                    if (row < M) {
                        int coln = ncol0 + nt * 16 + l15;
                        float v = acc[mt][nt][q];
                        if (relu) v = fmaxf(v, 0.f);
                        if (out_f32) ((float*)Cv)[(size_t)row * N + coln] = v;
                        else ((unsigned short*)Cv)[(size_t)row * N + coln] = f2bf(v);
                    }
                }
    } else {
        // ---- scalar f32 path (embedding GEMM only: N=128, A f32 global) ----
        float* sAf = (float*)sA;                  // 16*128 f32 = 8192 B
        const float* A = (const float*)Av;
        const int col = tid & 127;
        const int rg  = tid >> 7;                 // 0 or 1
        for (int t = 0; t < 4; t++) {
            const int sub0 = row0 + t * 16;
            for (int i = tid; i < 16 * 128; i += 256) {
                int r = i >> 7, k = i & 127;
                int gr = sub0 + r;
                sAf[i] = (gr < M) ? A[(size_t)gr * 128 + k] : 0.f;
            }
            __syncthreads();

            float acc[8];
            float b0 = bias ? bias[col] : 0.f;
            #pragma unroll
            for (int r8 = 0; r8 < 8; r8++) acc[r8] = b0;
            for (int k = 0; k < 128; k++) {
                float bvv = Bf[(size_t)k * 128 + col];
                #pragma unroll
                for (int r8 = 0; r8 < 8; r8++)
                    acc[r8] += sAf[(rg * 8 + r8) * 128 + k] * bvv;
            }
            #pragma unroll
            for (int r8 = 0; r8 < 8; r8++) {
                int row = sub0 + rg * 8 + r8;
                if (row < M) {
                    float a = acc[r8];
                    if (relu) a = fmaxf(a, 0.f);
                    if (out_f32) ((float*)Cv)[(size_t)row * 128 + col] = a;
                    else ((unsigned short*)Cv)[(size_t)row * 128 + col] = f2bf(a);
                }
            }
            __syncthreads();
        }
    }
}

__global__ void alpha_kernel(const unsigned short* xw,
                             const float* a_s, const float* a_d,
                             float* alpha_s, float* alpha_d) {
    int wave = threadIdx.x >> 6, lane = threadIdx.x & 63;
    int n = blockIdx.x * 4 + wave;
    if (n >= NNODES) return;
    float v0 = bf2f(xw[(size_t)n * HDIM + lane]);
    float v1 = bf2f(xw[(size_t)n * HDIM + 64 + lane]);
    float ds = v0 * a_s[lane] + v1 * a_s[64 + lane];
    float dd = v0 * a_d[lane] + v1 * a_d[64 + lane];
    for (int d = 32; d >= 1; d >>= 1) { ds += __shfl_xor(ds, d); dd += __shfl_xor(dd, d); }
    if (lane == 0) { alpha_s[n] = ds; alpha_d[n] = dd; }
}

// ---- CSR build (group edges by dst) ----
__global__ void count_kernel(const int* e32, const int* iflag, int* cnt) {
    int e = blockIdx.x * 256 + threadIdx.x;
    if (e < NEDGES) atomicAdd(&cnt[eget(e32, iflag, 1, e)], 1);
}
__global__ void scan1_kernel(const int* cnt, int* off, int* bsum) {
    __shared__ int s[256];
    int t = threadIdx.x, i = blockIdx.x * 256 + t;
    int v = (i < NNODES) ? cnt[i] : 0;
    s[t] = v;
    __syncthreads();
    for (int d = 1; d < 256; d <<= 1) {
        int add = (t >= d) ? s[t - d] : 0;
        __syncthreads();
        s[t] += add;
        __syncthreads();
    }
    if (i < NNODES) off[i] = s[t] - v;          // exclusive
    if (t == 255) bsum[blockIdx.x] = s[255];
}
__global__ void scan2_kernel(int* bsum, int nblk) {
    if (threadIdx.x == 0 && blockIdx.x == 0) {
        int run = 0;
        for (int c = 0; c < nblk; c++) { int t = bsum[c]; bsum[c] = run; run += t; }
    }
}
__global__ void scan3_kernel(int* off, const int* bsum) {
    int i = blockIdx.x * 256 + threadIdx.x;
    if (i < NNODES) off[i] += bsum[blockIdx.x];
}
__global__ void fill_kernel(const int* e32, const int* iflag, const int* off,
                            int* cur, int* csr_src, int* csr_dst, int* csr_eid,
                            int use_csr) {
    int e = blockIdx.x * 256 + threadIdx.x;
    if (e < NEDGES) {
        int sidx = eget(e32, iflag, 0, e);
        int d = eget(e32, iflag, 1, e);
        int p = atomicAdd(&cur[d], 1);
        int pos = off[d] + p;
        csr_src[pos] = sidx;
        if (use_csr) {
            csr_dst[pos] = d;
            csr_eid[pos] = e;
        }
    }
}

// GAT aggregation: one wave per node; h = relu(h + agg + b) in place.
// 64 lanes = 4 edge-slots x 16 feature-lanes; idx+alpha prefetched and
// shfl-broadcast so only the xw row gather remains in the hot loop.
__global__ void aggregate_kernel(const unsigned short* __restrict__ xw,
                                 const float* __restrict__ as_, const float* __restrict__ ad_,
                                 const int* __restrict__ off, const int* __restrict__ csr_src,
                                 const float* __restrict__ gat_b, unsigned short* __restrict__ h) {
    int wave = threadIdx.x >> 6, lane = threadIdx.x & 63;
    int n = blockIdx.x * 4 + wave;
    if (n >= NNODES) return;
    int o0 = off[n];
    int o1 = (n == NNODES - 1) ? NEDGES : off[n + 1];
    int deg = o1 - o0;
    float adn = ad_[n];
    float lself = leaky(as_[n] + adn);

    int deg64 = deg < 64 ? deg : 64;
    int idxv = 0; float av = 0.f;
    if (lane < deg64) { idxv = csr_src[o0 + lane]; av = as_[idxv]; }

    float m = lself;
    if (lane < deg64) m = fmaxf(m, leaky(av + adn));
    for (int i = 64 + lane; i < deg; i += 64) {
        int s = csr_src[o0 + i];
        m = fmaxf(m, leaky(as_[s] + adn));
    }
    #pragma unroll
    for (int d = 32; d >= 1; d >>= 1) m = fmaxf(m, __shfl_xor(m, d));

    const int slot = lane >> 4;
    const int l15  = lane & 15;
    float denom = 0.f;
    float acc[8];
    #pragma unroll
    for (int k = 0; k < 8; k++) acc[k] = 0.f;

    for (int t0 = 0; t0 < deg64; t0 += 4) {
        int i = t0 + slot;
        int sidx   = __shfl(idxv, i);
        float aval = __shfl(av, i);
        if (i < deg64) {
            float p = __expf(leaky(aval + adn) - m);
            denom += p;
            uint4 rv = *(const uint4*)(xw + (size_t)sidx * HDIM + l15 * 8);
            const unsigned short* rp = (const unsigned short*)&rv;
            #pragma unroll
            for (int k = 0; k < 8; k++) acc[k] += p * bf2f(rp[k]);
        }
    }
    for (int i = 64 + slot; i < deg; i += 4) {
        int s = csr_src[o0 + i];
        float p = __expf(leaky(as_[s] + adn) - m);
        denom += p;
        uint4 rv = *(const uint4*)(xw + (size_t)s * HDIM + l15 * 8);
        const unsigned short* rp = (const unsigned short*)&rv;
        #pragma unroll
        for (int k = 0; k < 8; k++) acc[k] += p * bf2f(rp[k]);
    }

    #pragma unroll
    for (int d = 16; d <= 32; d <<= 1) {
        denom += __shfl_xor(denom, d);
        #pragma unroll
        for (int k = 0; k < 8; k++) acc[k] += __shfl_xor(acc[k], d);
    }

    float ps = __expf(lself - m);
    denom += ps;
    uint4 sv = *(const uint4*)(xw + (size_t)n * HDIM + l15 * 8);
    const unsigned short* sp = (const unsigned short*)&sv;
    #pragma unroll
    for (int k = 0; k < 8; k++) acc[k] += ps * bf2f(sp[k]);

    if (slot == 0) {
        float inv = 1.f / denom;
        size_t base = (size_t)n * HDIM + l15 * 8;
        uint4 hv = *(const uint4*)(h + base);
        const unsigned short* hp = (const unsigned short*)&hv;
        unsigned short outv[8];
        #pragma unroll
        for (int k = 0; k < 8; k++) {
            float hx = bf2f(hp[k]);
            float bx = gat_b[l15 * 8 + k];
            outv[k] = f2bf(fmaxf(hx + acc[k] * inv + bx, 0.f));
        }
        *(uint4*)(h + base) = *(uint4*)outv;
    }
}

// ---------------------------------------------------------------------------
// Edge MLP via algebraic split (A = h@We1_top + be1, B = h@We1_bot per node):
// per edge v = relu(A[src]+B[dst]); out = v @ We2 + be2. Barrier-free.
// ---------------------------------------------------------------------------
__global__ __launch_bounds__(256) void edge_split_kernel(
    const unsigned short* __restrict__ A, const unsigned short* __restrict__ B,
    const int* __restrict__ e32, const int* __restrict__ iflag,
    const int* __restrict__ csr_src, const int* __restrict__ csr_dst,
    const int* __restrict__ csr_eid, int use_csr,
    const float* __restrict__ We2, const float* __restrict__ be2,
    float* __restrict__ eout)
{
    const int lane = threadIdx.x & 63;
    const int slot = lane >> 4, l15 = lane & 15;

    float w2[8][3];
    #pragma unroll
    for (int j = 0; j < 8; j++)
        #pragma unroll
        for (int c = 0; c < 3; c++)
            w2[j][c] = We2[(l15 * 8 + j) * 3 + c];
    const float bo0 = be2[0], bo1 = be2[1], bo2 = be2[2];

    const int gw = (blockIdx.x * 256 + threadIdx.x) >> 6;
    const int stride = gridDim.x * 16;
    for (int e = gw * 4 + slot; e < NEDGES; e += stride) {
        int s, d, oe;
        if (use_csr) { s = csr_src[e]; d = csr_dst[e]; oe = csr_eid[e]; }
        else {
            s = eget(e32, iflag, 0, e);
            d = eget(e32, iflag, 1, e);
            oe = e;
        }
        uint4 avv = *(const uint4*)(A + (size_t)s * HDIM + l15 * 8);
        uint4 bvv = *(const uint4*)(B + (size_t)d * HDIM + l15 * 8);
        const unsigned short* ap = (const unsigned short*)&avv;
        const unsigned short* bp = (const unsigned short*)&bvv;
        float s0 = 0.f, s1 = 0.f, s2 = 0.f;
        #pragma unroll
        for (int j = 0; j < 8; j++) {
            float v = fmaxf(bf2f(ap[j]) + bf2f(bp[j]), 0.f);
            s0 += v * w2[j][0]; s1 += v * w2[j][1]; s2 += v * w2[j][2];
        }
        #pragma unroll
        for (int dd = 1; dd < 16; dd <<= 1) {
            s0 += __shfl_xor(s0, dd);
            s1 += __shfl_xor(s1, dd);
            s2 += __shfl_xor(s2, dd);
        }
        if (l15 == 0) {
            eout[(size_t)oe * 3 + 0] = s0 + bo0;
            eout[(size_t)oe * 3 + 1] = s1 + bo1;
            eout[(size_t)oe * 3 + 2] = s2 + bo2;
        }
    }
}

__global__ void gsum_kernel(const unsigned short* h, float* gsum) {
    int f = threadIdx.x;
    float local = 0.f;
    int n0 = blockIdx.x * 200;
    for (int j = 0; j < 200; j++) local += bf2f(h[(size_t)(n0 + j) * HDIM + f]);
    atomicAdd(&gsum[f], local);
}
__global__ void gout_kernel(const float* gsum, float* out) {
    int f = threadIdx.x;
    out[GEMB_OFF + f] = gsum[f] * (1.f / (float)NNODES);
}

extern "C" __attribute__((visibility("default")))
void kernel_launch(void* const* d_in, const int* in_sizes, int n_in,
                   void* d_out, int out_size, void* d_ws, size_t ws_size,
                   hipStream_t stream) {
    const void* x      = d_in[0];
    const int*  eidx   = (const int*)d_in[1];
    const void* W_emb  = d_in[2];
    const void* b_emb  = d_in[3];
    const void* gat_W  = d_in[4];
    const void* gat_as = d_in[5];
    const void* gat_ad = d_in[6];
    const void* gat_b  = d_in[7];
    const void* Wn1    = d_in[8];
    const void* bn1    = d_in[9];
    const void* Wn2    = d_in[10];
    const void* bn2    = d_in[11];
    const void* We1    = d_in[12];
    const void* be1    = d_in[13];
    const void* We2    = d_in[14];
    const void* be2    = d_in[15];
    float* out = (float*)d_out;   // output dtype: float32

    char* ws = (char*)d_ws;
    unsigned short* h       = (unsigned short*)(ws);                // 12.8 MB
    unsigned short* xw      = (unsigned short*)(ws + 12800000);     // 12.8 MB
    float*          alpha_s = (float*)(ws + 25600000);              // 200 KB
    float*          alpha_d = (float*)(ws + 25800000);              // 200 KB
    int*            cnt     = (int*)(ws + 26000000);                // 200 KB
    int*            off     = (int*)(ws + 26200000);                // 200 KB
    int*            bsum    = (int*)(ws + 26400000);                // 1 KB
    float*          gsum    = (float*)(ws + 26401024);              // 512 B
    int*            iflag   = (int*)(ws + 26401536);
    int*            fflag   = (int*)(ws + 26401540);
    float*          We1c    = (float*)(ws + 26402048);              // 128 KB
    float*          We2c    = (float*)(ws + 26533120);
    float*          asc     = (float*)(ws + 26534656);
    float*          adc     = (float*)(ws + 26536192);
    float*          gbc     = (float*)(ws + 26537728);
    float*          bembc   = (float*)(ws + 26539264);
    float*          bn1c    = (float*)(ws + 26539776);
    float*          bn2c    = (float*)(ws + 26540288);
    float*          be1c    = (float*)(ws + 26540544);
    float*          be2c    = (float*)(ws + 26541056);
    float*          Wlc     = (float*)(ws + 26542080);              // 64 KB
    int*            csr_src = (int*)(ws + 26608000);                // 3.2 MB -> 29.81 MB
    int*            csr_dst = (int*)(ws + 29808000);                // 3.2 MB (optional)
    int*            csr_eid = (int*)(ws + 33008000);                // 3.2 MB -> 36.21 MB (optional)

    // Temporal-reuse aliases (zero extra footprint):
    float* Wembc = (float*)(ws + 26200000);        // in 'off' region, dead before scan1
    float* Wn1c = (float*)(ws + 26000000);         // in 'cnt' region, after fill
    float* Wn2c = (float*)(ws + 26065536);

    const int use_csr = (ws_size >= (size_t)36208000) ? 1 : 0;

    const int node_blks = (NNODES + 255) / 256;    // 196
    const int edge_blks = (NEDGES + 255) / 256;    // 3125
    const int g64       = (NNODES + 63) / 64;      // 782

    zero_int_kernel<<<1, 256, 0, stream>>>(iflag, 2);
    zero_int_kernel<<<node_blks, 256, 0, stream>>>(cnt, NNODES);
    zero_f32_kernel<<<1, 256, 0, stream>>>(gsum, HDIM);

    detect_f32_kernel<<<1, 256, 0, stream>>>((const unsigned short*)x, fflag);
    detect_i64_kernel<<<1, 256, 0, stream>>>(eidx, iflag);

    cvt_kernel<<<128, 256, 0, stream>>>(We1, We1c, 256 * 128, fflag);
    cvt_kernel<<<2, 256, 0, stream>>>(We2, We2c, 128 * 3, fflag);
    cvt_kernel<<<2, 256, 0, stream>>>(gat_as, asc, 3 * 128, fflag);
    cvt_kernel<<<2, 256, 0, stream>>>(gat_ad, adc, 3 * 128, fflag);
    cvt_kernel<<<2, 256, 0, stream>>>(gat_b, gbc, 3 * 128, fflag);
    cvt_kernel<<<1, 256, 0, stream>>>(b_emb, bembc, 128, fflag);
    cvt_kernel<<<1, 256, 0, stream>>>(bn1, bn1c, 128, fflag);
    cvt_kernel<<<1, 256, 0, stream>>>(bn2, bn2c, 64, fflag);
    cvt_kernel<<<1, 256, 0, stream>>>(be1, be1c, 128, fflag);
    cvt_kernel<<<1, 256, 0, stream>>>(be2, be2c, 3, fflag);
    cvt_kernel<<<64, 256, 0, stream>>>(W_emb, Wembc, 128 * 128, fflag);

    // h = relu(x @ W_emb + b_emb)   (a_dyn=1: scalar f32 path when input f32)
    gemm_mfma_kernel<<<g64, 256, 0, stream>>>(
        x, 1, Wembc, bembc, h, 0, NNODES, 128, 1, fflag);

    // CSR build (once); Wembc consumed before scan1 writes 'off'.
    count_kernel<<<edge_blks, 256, 0, stream>>>(eidx, iflag, cnt);
    scan1_kernel<<<node_blks, 256, 0, stream>>>(cnt, off, bsum);
    scan2_kernel<<<1, 64, 0, stream>>>(bsum, node_blks);
    scan3_kernel<<<node_blks, 256, 0, stream>>>(off, bsum);
    zero_int_kernel<<<node_blks, 256, 0, stream>>>(cnt, NNODES);
    fill_kernel<<<edge_blks, 256, 0, stream>>>(eidx, iflag, off, cnt,
                                               csr_src, csr_dst, csr_eid, use_csr);

    // cnt region now dead -> stash node-MLP weights there.
    cvt_kernel<<<64, 256, 0, stream>>>(Wn1, Wn1c, 128 * 128, fflag);
    cvt_kernel<<<32, 256, 0, stream>>>(Wn2, Wn2c, 128 * 64, fflag);

    for (int l = 0; l < NLAYERS; l++) {
        cvt_layerW_kernel<<<64, 256, 0, stream>>>(gat_W, Wlc, l, fflag);
        gemm_mfma_kernel<<<g64, 256, 0, stream>>>(
            h, 0, Wlc, (const float*)0, xw, 0, NNODES, 128, 0, fflag);
        alpha_kernel<<<(NNODES + 3) / 4, 256, 0, stream>>>(
            xw, asc + l * HDIM, adc + l * HDIM, alpha_s, alpha_d);
        aggregate_kernel<<<(NNODES + 3) / 4, 256, 0, stream>>>(
            xw, alpha_s, alpha_d, off, csr_src, gbc + l * HDIM, h);
    }

    // node MLP
    gemm_mfma_kernel<<<g64, 256, 0, stream>>>(
        h, 0, Wn1c, bn1c, xw, 0, NNODES, 128, 1, fflag);
    gemm_mfma_kernel<<<g64, 256, 0, stream>>>(
        xw, 0, Wn2c, bn2c, out, 1, NNODES, 64, 0, fflag);

    // graph embedding (must precede the in-place B GEMM that overwrites h)
    gsum_kernel<<<NNODES / 200, 128, 0, stream>>>(h, gsum);
    gout_kernel<<<1, 128, 0, stream>>>(gsum, out);

    // edge MLP via split: A = h@We1_top + be1 -> xw; B = h@We1_bot -> h (in place)
    gemm_mfma_kernel<<<g64, 256, 0, stream>>>(
        h, 0, We1c, be1c, xw, 0, NNODES, 128, 0, fflag);
    gemm_mfma_kernel<<<g64, 256, 0, stream>>>(
        h, 0, We1c + 128 * 128, (const float*)0, h, 0, NNODES, 128, 0, fflag);
    edge_split_kernel<<<2048, 256, 0, stream>>>(
        xw, h, eidx, iflag, csr_src, csr_dst, csr_eid, use_csr,
        We2c, be2c, out + NODE_OUT_ELEMS);
}

// Round 6
// 635.770 us; speedup vs baseline: 7.3212x; 7.1420x over previous
//
#include <hip/hip_runtime.h>

#define NNODES 50000
#define NEDGES 800000
#define HDIM 128
#define DOUT 64
#define NLAYERS 3
#define NEG_SLOPE 0.2f

#define NODE_OUT_ELEMS (NNODES * DOUT)             // 3,200,000
#define EDGE_OUT_ELEMS (NEDGES * 3)                // 2,400,000
#define GEMB_OFF (NODE_OUT_ELEMS + EDGE_OUT_ELEMS) // 5,600,000

typedef __attribute__((ext_vector_type(8))) short short8;
typedef __attribute__((ext_vector_type(4))) float f32x4;

__device__ __forceinline__ float bf2f(unsigned short u) {
    union { unsigned int i; float f; } v; v.i = ((unsigned int)u) << 16; return v.f;
}
__device__ __forceinline__ unsigned short f2bf(float f) {
    union { unsigned int i; float f; } v; v.f = f;
    unsigned int b = v.i;
    unsigned int r = (b + 0x7FFFu + ((b >> 16) & 1u)) >> 16;
    return (unsigned short)r;
}
__device__ __forceinline__ float leaky(float x) { return x > 0.f ? x : NEG_SLOPE * x; }

// Edge fetch: which=0 -> src, which=1 -> dst. iflag=1 -> int32, 0 -> int64.
__device__ __forceinline__ int eget(const int* e32, const int* iflag, int which, int e) {
    int idx = which * NEDGES + e;
    return (*iflag) ? e32[idx] : e32[2 * idx];
}

__global__ void zero_int_kernel(int* p, int n) {
    int i = blockIdx.x * 256 + threadIdx.x;
    if (i < n) p[i] = 0;
}
__global__ void zero_f32_kernel(float* p, int n) {
    int i = blockIdx.x * 256 + threadIdx.x;
    if (i < n) p[i] = 0.f;
}

__global__ void detect_f32_kernel(const unsigned short* xb, int* flag) {
    int hit = 0;
    for (int j = threadIdx.x; j < 4096; j += 256) {
        int e = (xb[j] >> 7) & 0xFF;
        if (e >= 0x90) hit = 1;
    }
    if (hit) atomicOr(flag, 1);
}
// Sampled int64 detection (one block, <=4 atomics).
__global__ void detect_i64_kernel(const int* e32, int* flag) {
    int hit = 0;
    for (int t = threadIdx.x; t < 16384; t += 256) {
        int i = t * 48;                       // 16383*48 = 786384 < NEDGES
        if (e32[2 * i + 1] != 0) hit = 1;
    }
    if (__any(hit)) {
        if ((threadIdx.x & 63) == 0) atomicOr(flag, 1);
    }
}

__global__ void cvt_kernel(const void* src, float* dst, int n, const int* f32flag) {
    int i = blockIdx.x * 256 + threadIdx.x;
    if (i < n)
        dst[i] = (*f32flag) ? ((const float*)src)[i]
                            : bf2f(((const unsigned short*)src)[i]);
}
__global__ void cvt_layerW_kernel(const void* gat_W, float* dst, int l,
                                  const int* f32flag) {
    int i = blockIdx.x * 256 + threadIdx.x;
    if (i < HDIM * HDIM) {
        size_t idx = (size_t)l * HDIM * HDIM + i;
        dst[i] = (*f32flag) ? ((const float*)gat_W)[idx]
                            : bf2f(((const unsigned short*)gat_W)[idx]);
    }
}

// ---------------------------------------------------------------------------
// GEMM: C[M,N] = op(A[M,128] @ B[128,N] + bias), N in {128, 64} (TEMPLATE —
// all fragment arrays statically indexed so they live in VGPRs, not scratch;
// round-5 lesson: runtime N put bw/acc in local memory -> 30x slowdown).
// MFMA path: A staged to LDS bf16; B rounded f32->bf16 (RNE) at fragment
// load; f32 accumulate. Fragment layout = hardware-validated edge_mlp_mfma.
// Scalar path: only a_dyn=1 && *f32flag (embedding GEMM, N=128); 4 sub-tiles
// of 16 rows, 8 acc/thread — bit-identical to proven round-3 gemm128.
// 256 threads = 4 waves; 64 rows/block.
// ---------------------------------------------------------------------------
template<int N>
__global__ __launch_bounds__(256) void gemm_mfma_kernel(
    const void* Av, int a_dyn, const float* __restrict__ Bf,
    const float* __restrict__ bias, void* Cv, int out_f32,
    int M, int relu, const int* __restrict__ f32flag)
{
    constexpr int KP = 128 + 8;
    constexpr int NTC = N >> 6;                   // 128 -> 2, 64 -> 1
    __shared__ unsigned short sA[64 * KP];        // 17,408 B (recast for scalar path)
    const int tid = threadIdx.x;
    const int row0 = blockIdx.x * 64;
    const int use_mfma = !(a_dyn && (*f32flag));

    if (use_mfma) {
        const unsigned short* A = (const unsigned short*)Av;
        for (int c = tid; c < 64 * 16; c += 256) {
            int r = c >> 4, cp = c & 15;
            int gr = row0 + r;
            uint4 v = {0u, 0u, 0u, 0u};
            if (gr < M) v = *(const uint4*)(A + (size_t)gr * 128 + cp * 8);
            *(uint4*)(&sA[r * KP + cp * 8]) = v;
        }
        __syncthreads();

        const int wave = tid >> 6, lane = tid & 63;
        const int quad = lane >> 4, l15 = lane & 15;
        const int ncol0 = wave * (NTC * 16);

        short8 bw[4][NTC];
        #pragma unroll
        for (int kk = 0; kk < 4; kk++)
            #pragma unroll
            for (int nt = 0; nt < NTC; nt++) {
                int n = ncol0 + nt * 16 + l15;
                short8 t;
                #pragma unroll
                for (int j = 0; j < 8; j++)
                    t[j] = (short)f2bf(Bf[(size_t)(kk * 32 + quad * 8 + j) * N + n]);
                bw[kk][nt] = t;
            }

        float bv[NTC];
        #pragma unroll
        for (int nt = 0; nt < NTC; nt++)
            bv[nt] = bias ? bias[ncol0 + nt * 16 + l15] : 0.f;

        f32x4 acc[4][NTC];
        #pragma unroll
        for (int mt = 0; mt < 4; mt++)
            #pragma unroll
            for (int nt = 0; nt < NTC; nt++) {
                acc[mt][nt][0] = bv[nt]; acc[mt][nt][1] = bv[nt];
                acc[mt][nt][2] = bv[nt]; acc[mt][nt][3] = bv[nt];
            }

        #pragma unroll
        for (int kk = 0; kk < 4; kk++) {
            short8 a[4];
            #pragma unroll
            for (int mt = 0; mt < 4; mt++)
                a[mt] = *(const short8*)(&sA[(mt * 16 + l15) * KP + kk * 32 + quad * 8]);
            #pragma unroll
            for (int mt = 0; mt < 4; mt++)
                #pragma unroll
                for (int nt = 0; nt < NTC; nt++)
                    acc[mt][nt] = __builtin_amdgcn_mfma_f32_16x16x32_bf16(
                        a[mt], bw[kk][nt], acc[mt][nt], 0, 0, 0);
        }

        #pragma unroll
        for (int mt = 0; mt < 4; mt++)
            #pragma unroll
            for (int nt = 0; nt < NTC; nt++)
                #pragma unroll
                for (int q = 0; q < 4; q++) {
                    int row = row0 + mt * 16 + quad * 4 + q;
                    if (row < M) {
                        int coln = ncol0 + nt * 16 + l15;
                        float v = acc[mt][nt][q];
                        if (relu) v = fmaxf(v, 0.f);
                        if (out_f32) ((float*)Cv)[(size_t)row * N + coln] = v;
                        else ((unsigned short*)Cv)[(size_t)row * N + coln] = f2bf(v);
                    }
                }
    } else {
        // ---- scalar f32 path (embedding GEMM only: N=128, A f32 global) ----
        float* sAf = (float*)sA;                  // 16*128 f32 = 8192 B
        const float* A = (const float*)Av;
        const int col = tid & 127;
        const int rg  = tid >> 7;                 // 0 or 1
        for (int t = 0; t < 4; t++) {
            const int sub0 = row0 + t * 16;
            for (int i = tid; i < 16 * 128; i += 256) {
                int r = i >> 7, k = i & 127;
                int gr = sub0 + r;
                sAf[i] = (gr < M) ? A[(size_t)gr * 128 + k] : 0.f;
            }
            __syncthreads();

            float acc[8];
            float b0 = bias ? bias[col] : 0.f;
            #pragma unroll
            for (int r8 = 0; r8 < 8; r8++) acc[r8] = b0;
            for (int k = 0; k < 128; k++) {
                float bvv = Bf[(size_t)k * 128 + col];
                #pragma unroll
                for (int r8 = 0; r8 < 8; r8++)
                    acc[r8] += sAf[(rg * 8 + r8) * 128 + k] * bvv;
            }
            #pragma unroll
            for (int r8 = 0; r8 < 8; r8++) {
                int row = sub0 + rg * 8 + r8;
                if (row < M) {
                    float a = acc[r8];
                    if (relu) a = fmaxf(a, 0.f);
                    if (out_f32) ((float*)Cv)[(size_t)row * 128 + col] = a;
                    else ((unsigned short*)Cv)[(size_t)row * 128 + col] = f2bf(a);
                }
            }
            __syncthreads();
        }
    }
}

__global__ void alpha_kernel(const unsigned short* xw,
                             const float* a_s, const float* a_d,
                             float* alpha_s, float* alpha_d) {
    int wave = threadIdx.x >> 6, lane = threadIdx.x & 63;
    int n = blockIdx.x * 4 + wave;
    if (n >= NNODES) return;
    float v0 = bf2f(xw[(size_t)n * HDIM + lane]);
    float v1 = bf2f(xw[(size_t)n * HDIM + 64 + lane]);
    float ds = v0 * a_s[lane] + v1 * a_s[64 + lane];
    float dd = v0 * a_d[lane] + v1 * a_d[64 + lane];
    for (int d = 32; d >= 1; d >>= 1) { ds += __shfl_xor(ds, d); dd += __shfl_xor(dd, d); }
    if (lane == 0) { alpha_s[n] = ds; alpha_d[n] = dd; }
}

// ---- CSR build (group edges by dst) ----
__global__ void count_kernel(const int* e32, const int* iflag, int* cnt) {
    int e = blockIdx.x * 256 + threadIdx.x;
    if (e < NEDGES) atomicAdd(&cnt[eget(e32, iflag, 1, e)], 1);
}
__global__ void scan1_kernel(const int* cnt, int* off, int* bsum) {
    __shared__ int s[256];
    int t = threadIdx.x, i = blockIdx.x * 256 + t;
    int v = (i < NNODES) ? cnt[i] : 0;
    s[t] = v;
    __syncthreads();
    for (int d = 1; d < 256; d <<= 1) {
        int add = (t >= d) ? s[t - d] : 0;
        __syncthreads();
        s[t] += add;
        __syncthreads();
    }
    if (i < NNODES) off[i] = s[t] - v;          // exclusive
    if (t == 255) bsum[blockIdx.x] = s[255];
}
__global__ void scan2_kernel(int* bsum, int nblk) {
    if (threadIdx.x == 0 && blockIdx.x == 0) {
        int run = 0;
        for (int c = 0; c < nblk; c++) { int t = bsum[c]; bsum[c] = run; run += t; }
    }
}
__global__ void scan3_kernel(int* off, const int* bsum) {
    int i = blockIdx.x * 256 + threadIdx.x;
    if (i < NNODES) off[i] += bsum[blockIdx.x];
}
__global__ void fill_kernel(const int* e32, const int* iflag, const int* off,
                            int* cur, int* csr_src, int* csr_dst, int* csr_eid,
                            int use_csr) {
    int e = blockIdx.x * 256 + threadIdx.x;
    if (e < NEDGES) {
        int sidx = eget(e32, iflag, 0, e);
        int d = eget(e32, iflag, 1, e);
        int p = atomicAdd(&cur[d], 1);
        int pos = off[d] + p;
        csr_src[pos] = sidx;
        if (use_csr) {
            csr_dst[pos] = d;
            csr_eid[pos] = e;
        }
    }
}

// GAT aggregation: one wave per node; h = relu(h + agg + b) in place.
// 64 lanes = 4 edge-slots x 16 feature-lanes; idx+alpha prefetched and
// shfl-broadcast so only the xw row gather remains in the hot loop.
__global__ void aggregate_kernel(const unsigned short* __restrict__ xw,
                                 const float* __restrict__ as_, const float* __restrict__ ad_,
                                 const int* __restrict__ off, const int* __restrict__ csr_src,
                                 const float* __restrict__ gat_b, unsigned short* __restrict__ h) {
    int wave = threadIdx.x >> 6, lane = threadIdx.x & 63;
    int n = blockIdx.x * 4 + wave;
    if (n >= NNODES) return;
    int o0 = off[n];
    int o1 = (n == NNODES - 1) ? NEDGES : off[n + 1];
    int deg = o1 - o0;
    float adn = ad_[n];
    float lself = leaky(as_[n] + adn);

    int deg64 = deg < 64 ? deg : 64;
    int idxv = 0; float av = 0.f;
    if (lane < deg64) { idxv = csr_src[o0 + lane]; av = as_[idxv]; }

    float m = lself;
    if (lane < deg64) m = fmaxf(m, leaky(av + adn));
    for (int i = 64 + lane; i < deg; i += 64) {
        int s = csr_src[o0 + i];
        m = fmaxf(m, leaky(as_[s] + adn));
    }
    #pragma unroll
    for (int d = 32; d >= 1; d >>= 1) m = fmaxf(m, __shfl_xor(m, d));

    const int slot = lane >> 4;
    const int l15  = lane & 15;
    float denom = 0.f;
    float acc[8];
    #pragma unroll
    for (int k = 0; k < 8; k++) acc[k] = 0.f;

    for (int t0 = 0; t0 < deg64; t0 += 4) {
        int i = t0 + slot;
        int sidx   = __shfl(idxv, i);
        float aval = __shfl(av, i);
        if (i < deg64) {
            float p = __expf(leaky(aval + adn) - m);
            denom += p;
            uint4 rv = *(const uint4*)(xw + (size_t)sidx * HDIM + l15 * 8);
            const unsigned short* rp = (const unsigned short*)&rv;
            #pragma unroll
            for (int k = 0; k < 8; k++) acc[k] += p * bf2f(rp[k]);
        }
    }
    for (int i = 64 + slot; i < deg; i += 4) {
        int s = csr_src[o0 + i];
        float p = __expf(leaky(as_[s] + adn) - m);
        denom += p;
        uint4 rv = *(const uint4*)(xw + (size_t)s * HDIM + l15 * 8);
        const unsigned short* rp = (const unsigned short*)&rv;
        #pragma unroll
        for (int k = 0; k < 8; k++) acc[k] += p * bf2f(rp[k]);
    }

    #pragma unroll
    for (int d = 16; d <= 32; d <<= 1) {
        denom += __shfl_xor(denom, d);
        #pragma unroll
        for (int k = 0; k < 8; k++) acc[k] += __shfl_xor(acc[k], d);
    }

    float ps = __expf(lself - m);
    denom += ps;
    uint4 sv = *(const uint4*)(xw + (size_t)n * HDIM + l15 * 8);
    const unsigned short* sp = (const unsigned short*)&sv;
    #pragma unroll
    for (int k = 0; k < 8; k++) acc[k] += ps * bf2f(sp[k]);

    if (slot == 0) {
        float inv = 1.f / denom;
        size_t base = (size_t)n * HDIM + l15 * 8;
        uint4 hv = *(const uint4*)(h + base);
        const unsigned short* hp = (const unsigned short*)&hv;
        unsigned short outv[8];
        #pragma unroll
        for (int k = 0; k < 8; k++) {
            float hx = bf2f(hp[k]);
            float bx = gat_b[l15 * 8 + k];
            outv[k] = f2bf(fmaxf(hx + acc[k] * inv + bx, 0.f));
        }
        *(uint4*)(h + base) = *(uint4*)outv;
    }
}

// ---------------------------------------------------------------------------
// Edge MLP via algebraic split (A = h@We1_top + be1, B = h@We1_bot per node):
// per edge v = relu(A[src]+B[dst]); out = v @ We2 + be2. Barrier-free.
// ---------------------------------------------------------------------------
__global__ __launch_bounds__(256) void edge_split_kernel(
    const unsigned short* __restrict__ A, const unsigned short* __restrict__ B,
    const int* __restrict__ e32, const int* __restrict__ iflag,
    const int* __restrict__ csr_src, const int* __restrict__ csr_dst,
    const int* __restrict__ csr_eid, int use_csr,
    const float* __restrict__ We2, const float* __restrict__ be2,
    float* __restrict__ eout)
{
    const int lane = threadIdx.x & 63;
    const int slot = lane >> 4, l15 = lane & 15;

    float w2[8][3];
    #pragma unroll
    for (int j = 0; j < 8; j++)
        #pragma unroll
        for (int c = 0; c < 3; c++)
            w2[j][c] = We2[(l15 * 8 + j) * 3 + c];
    const float bo0 = be2[0], bo1 = be2[1], bo2 = be2[2];

    const int gw = (blockIdx.x * 256 + threadIdx.x) >> 6;
    const int stride = gridDim.x * 16;
    for (int e = gw * 4 + slot; e < NEDGES; e += stride) {
        int s, d, oe;
        if (use_csr) { s = csr_src[e]; d = csr_dst[e]; oe = csr_eid[e]; }
        else {
            s = eget(e32, iflag, 0, e);
            d = eget(e32, iflag, 1, e);
            oe = e;
        }
        uint4 avv = *(const uint4*)(A + (size_t)s * HDIM + l15 * 8);
        uint4 bvv = *(const uint4*)(B + (size_t)d * HDIM + l15 * 8);
        const unsigned short* ap = (const unsigned short*)&avv;
        const unsigned short* bp = (const unsigned short*)&bvv;
        float s0 = 0.f, s1 = 0.f, s2 = 0.f;
        #pragma unroll
        for (int j = 0; j < 8; j++) {
            float v = fmaxf(bf2f(ap[j]) + bf2f(bp[j]), 0.f);
            s0 += v * w2[j][0]; s1 += v * w2[j][1]; s2 += v * w2[j][2];
        }
        #pragma unroll
        for (int dd = 1; dd < 16; dd <<= 1) {
            s0 += __shfl_xor(s0, dd);
            s1 += __shfl_xor(s1, dd);
            s2 += __shfl_xor(s2, dd);
        }
        if (l15 == 0) {
            eout[(size_t)oe * 3 + 0] = s0 + bo0;
            eout[(size_t)oe * 3 + 1] = s1 + bo1;
            eout[(size_t)oe * 3 + 2] = s2 + bo2;
        }
    }
}

__global__ void gsum_kernel(const unsigned short* h, float* gsum) {
    int f = threadIdx.x;
    float local = 0.f;
    int n0 = blockIdx.x * 200;
    for (int j = 0; j < 200; j++) local += bf2f(h[(size_t)(n0 + j) * HDIM + f]);
    atomicAdd(&gsum[f], local);
}
__global__ void gout_kernel(const float* gsum, float* out) {
    int f = threadIdx.x;
    out[GEMB_OFF + f] = gsum[f] * (1.f / (float)NNODES);
}

extern "C" __attribute__((visibility("default")))
void kernel_launch(void* const* d_in, const int* in_sizes, int n_in,
                   void* d_out, int out_size, void* d_ws, size_t ws_size,
                   hipStream_t stream) {
    const void* x      = d_in[0];
    const int*  eidx   = (const int*)d_in[1];
    const void* W_emb  = d_in[2];
    const void* b_emb  = d_in[3];
    const void* gat_W  = d_in[4];
    const void* gat_as = d_in[5];
    const void* gat_ad = d_in[6];
    const void* gat_b  = d_in[7];
    const void* Wn1    = d_in[8];
    const void* bn1    = d_in[9];
    const void* Wn2    = d_in[10];
    const void* bn2    = d_in[11];
    const void* We1    = d_in[12];
    const void* be1    = d_in[13];
    const void* We2    = d_in[14];
    const void* be2    = d_in[15];
    float* out = (float*)d_out;   // output dtype: float32

    char* ws = (char*)d_ws;
    unsigned short* h       = (unsigned short*)(ws);                // 12.8 MB
    unsigned short* xw      = (unsigned short*)(ws + 12800000);     // 12.8 MB
    float*          alpha_s = (float*)(ws + 25600000);              // 200 KB
    float*          alpha_d = (float*)(ws + 25800000);              // 200 KB
    int*            cnt     = (int*)(ws + 26000000);                // 200 KB
    int*            off     = (int*)(ws + 26200000);                // 200 KB
    int*            bsum    = (int*)(ws + 26400000);                // 1 KB
    float*          gsum    = (float*)(ws + 26401024);              // 512 B
    int*            iflag   = (int*)(ws + 26401536);
    int*            fflag   = (int*)(ws + 26401540);
    float*          We1c    = (float*)(ws + 26402048);              // 128 KB
    float*          We2c    = (float*)(ws + 26533120);
    float*          asc     = (float*)(ws + 26534656);
    float*          adc     = (float*)(ws + 26536192);
    float*          gbc     = (float*)(ws + 26537728);
    float*          bembc   = (float*)(ws + 26539264);
    float*          bn1c    = (float*)(ws + 26539776);
    float*          bn2c    = (float*)(ws + 26540288);
    float*          be1c    = (float*)(ws + 26540544);
    float*          be2c    = (float*)(ws + 26541056);
    float*          Wlc     = (float*)(ws + 26542080);              // 64 KB
    int*            csr_src = (int*)(ws + 26608000);                // 3.2 MB -> 29.81 MB
    int*            csr_dst = (int*)(ws + 29808000);                // 3.2 MB (optional)
    int*            csr_eid = (int*)(ws + 33008000);                // 3.2 MB -> 36.21 MB (optional)

    // Temporal-reuse aliases (zero extra footprint):
    float* Wembc = (float*)(ws + 26200000);        // in 'off' region, dead before scan1
    float* Wn1c = (float*)(ws + 26000000);         // in 'cnt' region, after fill
    float* Wn2c = (float*)(ws + 26065536);

    const int use_csr = (ws_size >= (size_t)36208000) ? 1 : 0;

    const int node_blks = (NNODES + 255) / 256;    // 196
    const int edge_blks = (NEDGES + 255) / 256;    // 3125
    const int g64       = (NNODES + 63) / 64;      // 782

    zero_int_kernel<<<1, 256, 0, stream>>>(iflag, 2);
    zero_int_kernel<<<node_blks, 256, 0, stream>>>(cnt, NNODES);
    zero_f32_kernel<<<1, 256, 0, stream>>>(gsum, HDIM);

    detect_f32_kernel<<<1, 256, 0, stream>>>((const unsigned short*)x, fflag);
    detect_i64_kernel<<<1, 256, 0, stream>>>(eidx, iflag);

    cvt_kernel<<<128, 256, 0, stream>>>(We1, We1c, 256 * 128, fflag);
    cvt_kernel<<<2, 256, 0, stream>>>(We2, We2c, 128 * 3, fflag);
    cvt_kernel<<<2, 256, 0, stream>>>(gat_as, asc, 3 * 128, fflag);
    cvt_kernel<<<2, 256, 0, stream>>>(gat_ad, adc, 3 * 128, fflag);
    cvt_kernel<<<2, 256, 0, stream>>>(gat_b, gbc, 3 * 128, fflag);
    cvt_kernel<<<1, 256, 0, stream>>>(b_emb, bembc, 128, fflag);
    cvt_kernel<<<1, 256, 0, stream>>>(bn1, bn1c, 128, fflag);
    cvt_kernel<<<1, 256, 0, stream>>>(bn2, bn2c, 64, fflag);
    cvt_kernel<<<1, 256, 0, stream>>>(be1, be1c, 128, fflag);
    cvt_kernel<<<1, 256, 0, stream>>>(be2, be2c, 3, fflag);
    cvt_kernel<<<64, 256, 0, stream>>>(W_emb, Wembc, 128 * 128, fflag);

    // h = relu(x @ W_emb + b_emb)   (a_dyn=1: scalar f32 path when input f32)
    gemm_mfma_kernel<128><<<g64, 256, 0, stream>>>(
        x, 1, Wembc, bembc, h, 0, NNODES, 1, fflag);

    // CSR build (once); Wembc consumed before scan1 writes 'off'.
    count_kernel<<<edge_blks, 256, 0, stream>>>(eidx, iflag, cnt);
    scan1_kernel<<<node_blks, 256, 0, stream>>>(cnt, off, bsum);
    scan2_kernel<<<1, 64, 0, stream>>>(bsum, node_blks);
    scan3_kernel<<<node_blks, 256, 0, stream>>>(off, bsum);
    zero_int_kernel<<<node_blks, 256, 0, stream>>>(cnt, NNODES);
    fill_kernel<<<edge_blks, 256, 0, stream>>>(eidx, iflag, off, cnt,
                                               csr_src, csr_dst, csr_eid, use_csr);

    // cnt region now dead -> stash node-MLP weights there.
    cvt_kernel<<<64, 256, 0, stream>>>(Wn1, Wn1c, 128 * 128, fflag);
    cvt_kernel<<<32, 256, 0, stream>>>(Wn2, Wn2c, 128 * 64, fflag);

    for (int l = 0; l < NLAYERS; l++) {
        cvt_layerW_kernel<<<64, 256, 0, stream>>>(gat_W, Wlc, l, fflag);
        gemm_mfma_kernel<128><<<g64, 256, 0, stream>>>(
            h, 0, Wlc, (const float*)0, xw, 0, NNODES, 0, fflag);
        alpha_kernel<<<(NNODES + 3) / 4, 256, 0, stream>>>(
            xw, asc + l * HDIM, adc + l * HDIM, alpha_s, alpha_d);
        aggregate_kernel<<<(NNODES + 3) / 4, 256, 0, stream>>>(
            xw, alpha_s, alpha_d, off, csr_src, gbc + l * HDIM, h);
    }

    // node MLP
    gemm_mfma_kernel<128><<<g64, 256, 0, stream>>>(
        h, 0, Wn1c, bn1c, xw, 0, NNODES, 1, fflag);
    gemm_mfma_kernel<64><<<g64, 256, 0, stream>>>(
        xw, 0, Wn2c, bn2c, out, 1, NNODES, 0, fflag);

    // graph embedding (must precede the in-place B GEMM that overwrites h)
    gsum_kernel<<<NNODES / 200, 128, 0, stream>>>(h, gsum);
    gout_kernel<<<1, 128, 0, stream>>>(gsum, out);

    // edge MLP via split: A = h@We1_top + be1 -> xw; B = h@We1_bot -> h (in place)
    gemm_mfma_kernel<128><<<g64, 256, 0, stream>>>(
        h, 0, We1c, be1c, xw, 0, NNODES, 0, fflag);
    gemm_mfma_kernel<128><<<g64, 256, 0, stream>>>(
        h, 0, We1c + 128 * 128, (const float*)0, h, 0, NNODES, 0, fflag);
    edge_split_kernel<<<2048, 256, 0, stream>>>(
        xw, h, eidx, iflag, csr_src, csr_dst, csr_eid, use_csr,
        We2c, be2c, out + NODE_OUT_ELEMS);
}

// Round 7
// 547.215 us; speedup vs baseline: 8.5060x; 1.1618x over previous
//
#include <hip/hip_runtime.h>

#define NNODES 50000
#define NEDGES 800000
#define HDIM 128
#define DOUT 64
#define NLAYERS 3
#define NEG_SLOPE 0.2f

#define NODE_OUT_ELEMS (NNODES * DOUT)             // 3,200,000
#define EDGE_OUT_ELEMS (NEDGES * 3)                // 2,400,000
#define GEMB_OFF (NODE_OUT_ELEMS + EDGE_OUT_ELEMS) // 5,600,000

typedef __attribute__((ext_vector_type(8))) short short8;
typedef __attribute__((ext_vector_type(4))) float f32x4;

__device__ __forceinline__ float bf2f(unsigned short u) {
    union { unsigned int i; float f; } v; v.i = ((unsigned int)u) << 16; return v.f;
}
__device__ __forceinline__ unsigned short f2bf(float f) {
    union { unsigned int i; float f; } v; v.f = f;
    unsigned int b = v.i;
    unsigned int r = (b + 0x7FFFu + ((b >> 16) & 1u)) >> 16;
    return (unsigned short)r;
}
__device__ __forceinline__ float leaky(float x) { return x > 0.f ? x : NEG_SLOPE * x; }

// Edge fetch: which=0 -> src, which=1 -> dst. iflag=1 -> int32, 0 -> int64.
__device__ __forceinline__ int eget(const int* e32, const int* iflag, int which, int e) {
    int idx = which * NEDGES + e;
    return (*iflag) ? e32[idx] : e32[2 * idx];
}

__global__ void zero_int_kernel(int* p, int n) {
    int i = blockIdx.x * 256 + threadIdx.x;
    if (i < n) p[i] = 0;
}
__global__ void zero_f32_kernel(float* p, int n) {
    int i = blockIdx.x * 256 + threadIdx.x;
    if (i < n) p[i] = 0.f;
}

__global__ void detect_f32_kernel(const unsigned short* xb, int* flag) {
    int hit = 0;
    for (int j = threadIdx.x; j < 4096; j += 256) {
        int e = (xb[j] >> 7) & 0xFF;
        if (e >= 0x90) hit = 1;
    }
    if (hit) atomicOr(flag, 1);
}
// Sampled int64 detection (one block, <=4 atomics).
__global__ void detect_i64_kernel(const int* e32, int* flag) {
    int hit = 0;
    for (int t = threadIdx.x; t < 16384; t += 256) {
        int i = t * 48;                       // 16383*48 = 786384 < NEDGES
        if (e32[2 * i + 1] != 0) hit = 1;
    }
    if (__any(hit)) {
        if ((threadIdx.x & 63) == 0) atomicOr(flag, 1);
    }
}

__global__ void cvt_kernel(const void* src, float* dst, int n, const int* f32flag) {
    int i = blockIdx.x * 256 + threadIdx.x;
    if (i < n)
        dst[i] = (*f32flag) ? ((const float*)src)[i]
                            : bf2f(((const unsigned short*)src)[i]);
}
__global__ void cvt_layerW_kernel(const void* gat_W, float* dst, int l,
                                  const int* f32flag) {
    int i = blockIdx.x * 256 + threadIdx.x;
    if (i < HDIM * HDIM) {
        size_t idx = (size_t)l * HDIM * HDIM + i;
        dst[i] = (*f32flag) ? ((const float*)gat_W)[idx]
                            : bf2f(((const unsigned short*)gat_W)[idx]);
    }
}

// Fused tiny-weight conversion: 9 segments in one launch.
struct SmallCvtArgs {
    const void* src[9];
    float*      dst[9];
    int         n[9];
};
__global__ void cvt_small_kernel(SmallCvtArgs a, const int* f32flag) {
    const int f = *f32flag;
    for (int s = 0; s < 9; s++) {
        int n = a.n[s];
        const void* sp = a.src[s];
        float* dp = a.dst[s];
        for (int i = blockIdx.x * 256 + threadIdx.x; i < n; i += gridDim.x * 256)
            dp[i] = f ? ((const float*)sp)[i]
                      : bf2f(((const unsigned short*)sp)[i]);
    }
}

// x -> bf16 (vectorized, 4 elems/thread). bf16 input: straight copy.
__global__ void cvt_x_bf16_kernel(const void* x, unsigned short* xb,
                                  const int* f32flag) {
    int i = (blockIdx.x * 256 + threadIdx.x) * 4;   // 6,400,000 total
    if (*f32flag) {
        float4 v = *(const float4*)((const float*)x + i);
        unsigned short o[4] = {f2bf(v.x), f2bf(v.y), f2bf(v.z), f2bf(v.w)};
        *(uint2*)(xb + i) = *(uint2*)o;
    } else {
        *(uint2*)(xb + i) = *(const uint2*)((const unsigned short*)x + i);
    }
}

// ---------------------------------------------------------------------------
// MFMA GEMM, N=128 fixed: C_bf16[M,128] = op(A_bf16[M,128] @ Bf[128,128] + bias).
// A staged to LDS; B fragments f32->bf16 (RNE); f32 accumulate.
// 256 threads = 4 waves, 64 rows/block. Fragment layout HW-validated (r0-r2).
// ---------------------------------------------------------------------------
__global__ __launch_bounds__(256) void gemm_mfma_kernel(
    const unsigned short* __restrict__ A, const float* __restrict__ Bf,
    const float* __restrict__ bias, unsigned short* __restrict__ C,
    int M, int relu)
{
    constexpr int KP = 128 + 8;
    __shared__ unsigned short sA[64 * KP];
    const int tid = threadIdx.x;
    const int row0 = blockIdx.x * 64;

    for (int c = tid; c < 64 * 16; c += 256) {
        int r = c >> 4, cp = c & 15;
        int gr = row0 + r;
        uint4 v = {0u, 0u, 0u, 0u};
        if (gr < M) v = *(const uint4*)(A + (size_t)gr * 128 + cp * 8);
        *(uint4*)(&sA[r * KP + cp * 8]) = v;
    }
    __syncthreads();

    const int wave = tid >> 6, lane = tid & 63;
    const int quad = lane >> 4, l15 = lane & 15;
    const int ncol0 = wave * 32;

    short8 bw[4][2];
    #pragma unroll
    for (int kk = 0; kk < 4; kk++)
        #pragma unroll
        for (int nt = 0; nt < 2; nt++) {
            int n = ncol0 + nt * 16 + l15;
            short8 t;
            #pragma unroll
            for (int j = 0; j < 8; j++)
                t[j] = (short)f2bf(Bf[(size_t)(kk * 32 + quad * 8 + j) * 128 + n]);
            bw[kk][nt] = t;
        }

    float bv[2];
    #pragma unroll
    for (int nt = 0; nt < 2; nt++)
        bv[nt] = bias ? bias[ncol0 + nt * 16 + l15] : 0.f;

    f32x4 acc[4][2];
    #pragma unroll
    for (int mt = 0; mt < 4; mt++)
        #pragma unroll
        for (int nt = 0; nt < 2; nt++) {
            acc[mt][nt][0] = bv[nt]; acc[mt][nt][1] = bv[nt];
            acc[mt][nt][2] = bv[nt]; acc[mt][nt][3] = bv[nt];
        }

    #pragma unroll
    for (int kk = 0; kk < 4; kk++) {
        short8 a[4];
        #pragma unroll
        for (int mt = 0; mt < 4; mt++)
            a[mt] = *(const short8*)(&sA[(mt * 16 + l15) * KP + kk * 32 + quad * 8]);
        #pragma unroll
        for (int mt = 0; mt < 4; mt++)
            #pragma unroll
            for (int nt = 0; nt < 2; nt++)
                acc[mt][nt] = __builtin_amdgcn_mfma_f32_16x16x32_bf16(
                    a[mt], bw[kk][nt], acc[mt][nt], 0, 0, 0);
    }

    #pragma unroll
    for (int mt = 0; mt < 4; mt++)
        #pragma unroll
        for (int nt = 0; nt < 2; nt++)
            #pragma unroll
            for (int q = 0; q < 4; q++) {
                int row = row0 + mt * 16 + quad * 4 + q;
                if (row < M) {
                    float v = acc[mt][nt][q];
                    if (relu) v = fmaxf(v, 0.f);
                    C[(size_t)row * 128 + ncol0 + nt * 16 + l15] = f2bf(v);
                }
            }
}

// ---------------------------------------------------------------------------
// Fused node MLP: out = relu(h@Wn1+bn1)@Wn2+bn2, t kept in LDS (bf16 —
// bit-identical to the old xw roundtrip). One h staging, one launch.
// ---------------------------------------------------------------------------
__global__ __launch_bounds__(256) void node_mlp_kernel(
    const unsigned short* __restrict__ h, const float* __restrict__ Wn1f,
    const float* __restrict__ bn1, const float* __restrict__ Wn2f,
    const float* __restrict__ bn2, float* __restrict__ out, int M)
{
    constexpr int KP = 128 + 8;
    __shared__ unsigned short sA[64 * KP];
    const int tid = threadIdx.x;
    const int row0 = blockIdx.x * 64;

    for (int c = tid; c < 64 * 16; c += 256) {
        int r = c >> 4, cp = c & 15;
        int gr = row0 + r;
        uint4 v = {0u, 0u, 0u, 0u};
        if (gr < M) v = *(const uint4*)(h + (size_t)gr * 128 + cp * 8);
        *(uint4*)(&sA[r * KP + cp * 8]) = v;
    }
    __syncthreads();

    const int wave = tid >> 6, lane = tid & 63;
    const int quad = lane >> 4, l15 = lane & 15;
    const int ncol0 = wave * 32;

    // ---- GEMM1: t = relu(h @ Wn1 + bn1), N=128 ----
    {
        short8 bw[4][2];
        #pragma unroll
        for (int kk = 0; kk < 4; kk++)
            #pragma unroll
            for (int nt = 0; nt < 2; nt++) {
                int n = ncol0 + nt * 16 + l15;
                short8 t;
                #pragma unroll
                for (int j = 0; j < 8; j++)
                    t[j] = (short)f2bf(Wn1f[(size_t)(kk * 32 + quad * 8 + j) * 128 + n]);
                bw[kk][nt] = t;
            }
        float bv[2];
        #pragma unroll
        for (int nt = 0; nt < 2; nt++) bv[nt] = bn1[ncol0 + nt * 16 + l15];

        f32x4 acc[4][2];
        #pragma unroll
        for (int mt = 0; mt < 4; mt++)
            #pragma unroll
            for (int nt = 0; nt < 2; nt++) {
                acc[mt][nt][0] = bv[nt]; acc[mt][nt][1] = bv[nt];
                acc[mt][nt][2] = bv[nt]; acc[mt][nt][3] = bv[nt];
            }
        #pragma unroll
        for (int kk = 0; kk < 4; kk++) {
            short8 a[4];
            #pragma unroll
            for (int mt = 0; mt < 4; mt++)
                a[mt] = *(const short8*)(&sA[(mt * 16 + l15) * KP + kk * 32 + quad * 8]);
            #pragma unroll
            for (int mt = 0; mt < 4; mt++)
                #pragma unroll
                for (int nt = 0; nt < 2; nt++)
                    acc[mt][nt] = __builtin_amdgcn_mfma_f32_16x16x32_bf16(
                        a[mt], bw[kk][nt], acc[mt][nt], 0, 0, 0);
        }
        __syncthreads();                         // all sA reads done
        #pragma unroll
        for (int mt = 0; mt < 4; mt++)
            #pragma unroll
            for (int nt = 0; nt < 2; nt++)
                #pragma unroll
                for (int q = 0; q < 4; q++) {
                    int r = mt * 16 + quad * 4 + q;
                    sA[r * KP + ncol0 + nt * 16 + l15] =
                        f2bf(fmaxf(acc[mt][nt][q], 0.f));
                }
        __syncthreads();                         // t ready
    }

    // ---- GEMM2: out = t @ Wn2 + bn2, N=64 ----
    {
        const int col = wave * 16 + l15;         // 4 waves x 16 = 64 cols
        short8 bw[4];
        #pragma unroll
        for (int kk = 0; kk < 4; kk++) {
            short8 t;
            #pragma unroll
            for (int j = 0; j < 8; j++)
                t[j] = (short)f2bf(Wn2f[(size_t)(kk * 32 + quad * 8 + j) * 64 + col]);
            bw[kk] = t;
        }
        float bv = bn2[col];
        f32x4 acc[4];
        #pragma unroll
        for (int mt = 0; mt < 4; mt++) {
            acc[mt][0] = bv; acc[mt][1] = bv; acc[mt][2] = bv; acc[mt][3] = bv;
        }
        #pragma unroll
        for (int kk = 0; kk < 4; kk++) {
            short8 a[4];
            #pragma unroll
            for (int mt = 0; mt < 4; mt++)
                a[mt] = *(const short8*)(&sA[(mt * 16 + l15) * KP + kk * 32 + quad * 8]);
            #pragma unroll
            for (int mt = 0; mt < 4; mt++)
                acc[mt] = __builtin_amdgcn_mfma_f32_16x16x32_bf16(
                    a[mt], bw[kk], acc[mt], 0, 0, 0);
        }
        #pragma unroll
        for (int mt = 0; mt < 4; mt++)
            #pragma unroll
            for (int q = 0; q < 4; q++) {
                int row = row0 + mt * 16 + quad * 4 + q;
                if (row < M) out[(size_t)row * 64 + col] = acc[mt][q];
            }
    }
}

// ---------------------------------------------------------------------------
// Fused edge A/B: stage h once; A = h@We1_top + be1 -> Axw (bf16);
// B = h@We1_bot -> Bh (bf16, in-place over h; block touches only own rows).
// ---------------------------------------------------------------------------
__global__ __launch_bounds__(256) void edge_ab_kernel(
    const unsigned short* __restrict__ h, const float* __restrict__ We1f,
    const float* __restrict__ be1, unsigned short* __restrict__ Axw,
    unsigned short* __restrict__ Bh, int M)
{
    constexpr int KP = 128 + 8;
    __shared__ unsigned short sA[64 * KP];
    const int tid = threadIdx.x;
    const int row0 = blockIdx.x * 64;

    for (int c = tid; c < 64 * 16; c += 256) {
        int r = c >> 4, cp = c & 15;
        int gr = row0 + r;
        uint4 v = {0u, 0u, 0u, 0u};
        if (gr < M) v = *(const uint4*)(h + (size_t)gr * 128 + cp * 8);
        *(uint4*)(&sA[r * KP + cp * 8]) = v;
    }
    __syncthreads();

    const int wave = tid >> 6, lane = tid & 63;
    const int quad = lane >> 4, l15 = lane & 15;
    const int ncol0 = wave * 32;

    #pragma unroll
    for (int half = 0; half < 2; half++) {
        const float* Bf = We1f + (size_t)half * 128 * 128;
        unsigned short* Cp = half ? Bh : Axw;

        short8 bw[4][2];
        #pragma unroll
        for (int kk = 0; kk < 4; kk++)
            #pragma unroll
            for (int nt = 0; nt < 2; nt++) {
                int n = ncol0 + nt * 16 + l15;
                short8 t;
                #pragma unroll
                for (int j = 0; j < 8; j++)
                    t[j] = (short)f2bf(Bf[(size_t)(kk * 32 + quad * 8 + j) * 128 + n]);
                bw[kk][nt] = t;
            }
        float bv[2];
        #pragma unroll
        for (int nt = 0; nt < 2; nt++)
            bv[nt] = half ? 0.f : be1[ncol0 + nt * 16 + l15];

        f32x4 acc[4][2];
        #pragma unroll
        for (int mt = 0; mt < 4; mt++)
            #pragma unroll
            for (int nt = 0; nt < 2; nt++) {
                acc[mt][nt][0] = bv[nt]; acc[mt][nt][1] = bv[nt];
                acc[mt][nt][2] = bv[nt]; acc[mt][nt][3] = bv[nt];
            }
        #pragma unroll
        for (int kk = 0; kk < 4; kk++) {
            short8 a[4];
            #pragma unroll
            for (int mt = 0; mt < 4; mt++)
                a[mt] = *(const short8*)(&sA[(mt * 16 + l15) * KP + kk * 32 + quad * 8]);
            #pragma unroll
            for (int mt = 0; mt < 4; mt++)
                #pragma unroll
                for (int nt = 0; nt < 2; nt++)
                    acc[mt][nt] = __builtin_amdgcn_mfma_f32_16x16x32_bf16(
                        a[mt], bw[kk][nt], acc[mt][nt], 0, 0, 0);
        }
        #pragma unroll
        for (int mt = 0; mt < 4; mt++)
            #pragma unroll
            for (int nt = 0; nt < 2; nt++)
                #pragma unroll
                for (int q = 0; q < 4; q++) {
                    int row = row0 + mt * 16 + quad * 4 + q;
                    if (row < M)
                        Cp[(size_t)row * 128 + ncol0 + nt * 16 + l15] =
                            f2bf(acc[mt][nt][q]);
                }
    }
}

__global__ void alpha_kernel(const unsigned short* xw,
                             const float* a_s, const float* a_d,
                             float* alpha_s, float* alpha_d) {
    int wave = threadIdx.x >> 6, lane = threadIdx.x & 63;
    int n = blockIdx.x * 4 + wave;
    if (n >= NNODES) return;
    float v0 = bf2f(xw[(size_t)n * HDIM + lane]);
    float v1 = bf2f(xw[(size_t)n * HDIM + 64 + lane]);
    float ds = v0 * a_s[lane] + v1 * a_s[64 + lane];
    float dd = v0 * a_d[lane] + v1 * a_d[64 + lane];
    for (int d = 32; d >= 1; d >>= 1) { ds += __shfl_xor(ds, d); dd += __shfl_xor(dd, d); }
    if (lane == 0) { alpha_s[n] = ds; alpha_d[n] = dd; }
}

// ---- CSR build (group edges by dst) ----
__global__ void count_kernel(const int* e32, const int* iflag, int* cnt) {
    int e = blockIdx.x * 256 + threadIdx.x;
    if (e < NEDGES) atomicAdd(&cnt[eget(e32, iflag, 1, e)], 1);
}
__global__ void scan1_kernel(const int* cnt, int* off, int* bsum) {
    __shared__ int s[256];
    int t = threadIdx.x, i = blockIdx.x * 256 + t;
    int v = (i < NNODES) ? cnt[i] : 0;
    s[t] = v;
    __syncthreads();
    for (int d = 1; d < 256; d <<= 1) {
        int add = (t >= d) ? s[t - d] : 0;
        __syncthreads();
        s[t] += add;
        __syncthreads();
    }
    if (i < NNODES) off[i] = s[t] - v;          // exclusive
    if (t == 255) bsum[blockIdx.x] = s[255];
}
__global__ void scan2_kernel(int* bsum, int nblk) {
    if (threadIdx.x == 0 && blockIdx.x == 0) {
        int run = 0;
        for (int c = 0; c < nblk; c++) { int t = bsum[c]; bsum[c] = run; run += t; }
    }
}
__global__ void scan3_kernel(int* off, const int* bsum) {
    int i = blockIdx.x * 256 + threadIdx.x;
    if (i < NNODES) off[i] += bsum[blockIdx.x];
}
__global__ void fill_kernel(const int* e32, const int* iflag, const int* off,
                            int* cur, int* csr_src, int* csr_dst, int* csr_eid,
                            int use_csr) {
    int e = blockIdx.x * 256 + threadIdx.x;
    if (e < NEDGES) {
        int sidx = eget(e32, iflag, 0, e);
        int d = eget(e32, iflag, 1, e);
        int p = atomicAdd(&cur[d], 1);
        int pos = off[d] + p;
        csr_src[pos] = sidx;
        if (use_csr) {
            csr_dst[pos] = d;
            csr_eid[pos] = e;
        }
    }
}

// GAT aggregation: one wave per node; h = relu(h + agg + b) in place.
// 64 lanes = 4 edge-slots x 16 feature-lanes; idx+alpha prefetched and
// shfl-broadcast so only the xw row gather remains in the hot loop.
__global__ void aggregate_kernel(const unsigned short* __restrict__ xw,
                                 const float* __restrict__ as_, const float* __restrict__ ad_,
                                 const int* __restrict__ off, const int* __restrict__ csr_src,
                                 const float* __restrict__ gat_b, unsigned short* __restrict__ h) {
    int wave = threadIdx.x >> 6, lane = threadIdx.x & 63;
    int n = blockIdx.x * 4 + wave;
    if (n >= NNODES) return;
    int o0 = off[n];
    int o1 = (n == NNODES - 1) ? NEDGES : off[n + 1];
    int deg = o1 - o0;
    float adn = ad_[n];
    float lself = leaky(as_[n] + adn);

    int deg64 = deg < 64 ? deg : 64;
    int idxv = 0; float av = 0.f;
    if (lane < deg64) { idxv = csr_src[o0 + lane]; av = as_[idxv]; }

    float m = lself;
    if (lane < deg64) m = fmaxf(m, leaky(av + adn));
    for (int i = 64 + lane; i < deg; i += 64) {
        int s = csr_src[o0 + i];
        m = fmaxf(m, leaky(as_[s] + adn));
    }
    #pragma unroll
    for (int d = 32; d >= 1; d >>= 1) m = fmaxf(m, __shfl_xor(m, d));

    const int slot = lane >> 4;
    const int l15  = lane & 15;
    float denom = 0.f;
    float acc[8];
    #pragma unroll
    for (int k = 0; k < 8; k++) acc[k] = 0.f;

    for (int t0 = 0; t0 < deg64; t0 += 4) {
        int i = t0 + slot;
        int sidx   = __shfl(idxv, i);
        float aval = __shfl(av, i);
        if (i < deg64) {
            float p = __expf(leaky(aval + adn) - m);
            denom += p;
            uint4 rv = *(const uint4*)(xw + (size_t)sidx * HDIM + l15 * 8);
            const unsigned short* rp = (const unsigned short*)&rv;
            #pragma unroll
            for (int k = 0; k < 8; k++) acc[k] += p * bf2f(rp[k]);
        }
    }
    for (int i = 64 + slot; i < deg; i += 4) {
        int s = csr_src[o0 + i];
        float p = __expf(leaky(as_[s] + adn) - m);
        denom += p;
        uint4 rv = *(const uint4*)(xw + (size_t)s * HDIM + l15 * 8);
        const unsigned short* rp = (const unsigned short*)&rv;
        #pragma unroll
        for (int k = 0; k < 8; k++) acc[k] += p * bf2f(rp[k]);
    }

    #pragma unroll
    for (int d = 16; d <= 32; d <<= 1) {
        denom += __shfl_xor(denom, d);
        #pragma unroll
        for (int k = 0; k < 8; k++) acc[k] += __shfl_xor(acc[k], d);
    }

    float ps = __expf(lself - m);
    denom += ps;
    uint4 sv = *(const uint4*)(xw + (size_t)n * HDIM + l15 * 8);
    const unsigned short* sp = (const unsigned short*)&sv;
    #pragma unroll
    for (int k = 0; k < 8; k++) acc[k] += ps * bf2f(sp[k]);

    if (slot == 0) {
        float inv = 1.f / denom;
        size_t base = (size_t)n * HDIM + l15 * 8;
        uint4 hv = *(const uint4*)(h + base);
        const unsigned short* hp = (const unsigned short*)&hv;
        unsigned short outv[8];
        #pragma unroll
        for (int k = 0; k < 8; k++) {
            float hx = bf2f(hp[k]);
            float bx = gat_b[l15 * 8 + k];
            outv[k] = f2bf(fmaxf(hx + acc[k] * inv + bx, 0.f));
        }
        *(uint4*)(h + base) = *(uint4*)outv;
    }
}

// ---------------------------------------------------------------------------
// Edge MLP final: per edge v = relu(A[src]+B[dst]); out = v @ We2 + be2.
// ---------------------------------------------------------------------------
__global__ __launch_bounds__(256) void edge_split_kernel(
    const unsigned short* __restrict__ A, const unsigned short* __restrict__ B,
    const int* __restrict__ e32, const int* __restrict__ iflag,
    const int* __restrict__ csr_src, const int* __restrict__ csr_dst,
    const int* __restrict__ csr_eid, int use_csr,
    const float* __restrict__ We2, const float* __restrict__ be2,
    float* __restrict__ eout)
{
    const int lane = threadIdx.x & 63;
    const int slot = lane >> 4, l15 = lane & 15;

    float w2[8][3];
    #pragma unroll
    for (int j = 0; j < 8; j++)
        #pragma unroll
        for (int c = 0; c < 3; c++)
            w2[j][c] = We2[(l15 * 8 + j) * 3 + c];
    const float bo0 = be2[0], bo1 = be2[1], bo2 = be2[2];

    const int gw = (blockIdx.x * 256 + threadIdx.x) >> 6;
    const int stride = gridDim.x * 16;
    for (int e = gw * 4 + slot; e < NEDGES; e += stride) {
        int s, d, oe;
        if (use_csr) { s = csr_src[e]; d = csr_dst[e]; oe = csr_eid[e]; }
        else {
            s = eget(e32, iflag, 0, e);
            d = eget(e32, iflag, 1, e);
            oe = e;
        }
        uint4 avv = *(const uint4*)(A + (size_t)s * HDIM + l15 * 8);
        uint4 bvv = *(const uint4*)(B + (size_t)d * HDIM + l15 * 8);
        const unsigned short* ap = (const unsigned short*)&avv;
        const unsigned short* bp = (const unsigned short*)&bvv;
        float s0 = 0.f, s1 = 0.f, s2 = 0.f;
        #pragma unroll
        for (int j = 0; j < 8; j++) {
            float v = fmaxf(bf2f(ap[j]) + bf2f(bp[j]), 0.f);
            s0 += v * w2[j][0]; s1 += v * w2[j][1]; s2 += v * w2[j][2];
        }
        #pragma unroll
        for (int dd = 1; dd < 16; dd <<= 1) {
            s0 += __shfl_xor(s0, dd);
            s1 += __shfl_xor(s1, dd);
            s2 += __shfl_xor(s2, dd);
        }
        if (l15 == 0) {
            eout[(size_t)oe * 3 + 0] = s0 + bo0;
            eout[(size_t)oe * 3 + 1] = s1 + bo1;
            eout[(size_t)oe * 3 + 2] = s2 + bo2;
        }
    }
}

__global__ void gsum_kernel(const unsigned short* h, float* gsum) {
    int f = threadIdx.x;
    float local = 0.f;
    int n0 = blockIdx.x * 200;
    for (int j = 0; j < 200; j++) local += bf2f(h[(size_t)(n0 + j) * HDIM + f]);
    atomicAdd(&gsum[f], local);
}
__global__ void gout_kernel(const float* gsum, float* out) {
    int f = threadIdx.x;
    out[GEMB_OFF + f] = gsum[f] * (1.f / (float)NNODES);
}

extern "C" __attribute__((visibility("default")))
void kernel_launch(void* const* d_in, const int* in_sizes, int n_in,
                   void* d_out, int out_size, void* d_ws, size_t ws_size,
                   hipStream_t stream) {
    const void* x      = d_in[0];
    const int*  eidx   = (const int*)d_in[1];
    const void* W_emb  = d_in[2];
    const void* b_emb  = d_in[3];
    const void* gat_W  = d_in[4];
    const void* gat_as = d_in[5];
    const void* gat_ad = d_in[6];
    const void* gat_b  = d_in[7];
    const void* Wn1    = d_in[8];
    const void* bn1    = d_in[9];
    const void* Wn2    = d_in[10];
    const void* bn2    = d_in[11];
    const void* We1    = d_in[12];
    const void* be1    = d_in[13];
    const void* We2    = d_in[14];
    const void* be2    = d_in[15];
    float* out = (float*)d_out;   // output dtype: float32

    char* ws = (char*)d_ws;
    unsigned short* h       = (unsigned short*)(ws);                // 12.8 MB
    unsigned short* xw      = (unsigned short*)(ws + 12800000);     // 12.8 MB
    float*          alpha_s = (float*)(ws + 25600000);              // 200 KB
    float*          alpha_d = (float*)(ws + 25800000);              // 200 KB
    int*            cnt     = (int*)(ws + 26000000);                // 200 KB
    int*            off     = (int*)(ws + 26200000);                // 200 KB
    int*            bsum    = (int*)(ws + 26400000);                // 1 KB
    float*          gsum    = (float*)(ws + 26401024);              // 512 B
    int*            iflag   = (int*)(ws + 26401536);
    int*            fflag   = (int*)(ws + 26401540);
    float*          We1c    = (float*)(ws + 26402048);              // 128 KB
    float*          We2c    = (float*)(ws + 26533120);
    float*          asc     = (float*)(ws + 26534656);
    float*          adc     = (float*)(ws + 26536192);
    float*          gbc     = (float*)(ws + 26537728);
    float*          bembc   = (float*)(ws + 26539264);
    float*          bn1c    = (float*)(ws + 26539776);
    float*          bn2c    = (float*)(ws + 26540288);
    float*          be1c    = (float*)(ws + 26540544);
    float*          be2c    = (float*)(ws + 26541056);
    float*          Wlc     = (float*)(ws + 26542080);              // 64 KB
    int*            csr_src = (int*)(ws + 26608000);                // 3.2 MB -> 29.81 MB
    int*            csr_dst = (int*)(ws + 29808000);                // 3.2 MB (optional)
    int*            csr_eid = (int*)(ws + 33008000);                // 3.2 MB -> 36.21 MB (optional)

    // Temporal-reuse aliases (zero extra footprint):
    float* Wembc = (float*)(ws + 26200000);        // in 'off' region, dead before scan1
    float* Wn1c = (float*)(ws + 26000000);         // in 'cnt' region, after fill
    float* Wn2c = (float*)(ws + 26065536);

    const int use_csr = (ws_size >= (size_t)36208000) ? 1 : 0;

    const int node_blks = (NNODES + 255) / 256;    // 196
    const int edge_blks = (NEDGES + 255) / 256;    // 3125
    const int g64       = (NNODES + 63) / 64;      // 782

    zero_int_kernel<<<1, 256, 0, stream>>>(iflag, 2);
    zero_int_kernel<<<node_blks, 256, 0, stream>>>(cnt, NNODES);
    zero_f32_kernel<<<1, 256, 0, stream>>>(gsum, HDIM);

    detect_f32_kernel<<<1, 256, 0, stream>>>((const unsigned short*)x, fflag);
    detect_i64_kernel<<<1, 256, 0, stream>>>(eidx, iflag);

    SmallCvtArgs sc;
    sc.src[0] = We2;   sc.dst[0] = We2c;  sc.n[0] = 128 * 3;
    sc.src[1] = gat_as; sc.dst[1] = asc;  sc.n[1] = 3 * 128;
    sc.src[2] = gat_ad; sc.dst[2] = adc;  sc.n[2] = 3 * 128;
    sc.src[3] = gat_b;  sc.dst[3] = gbc;  sc.n[3] = 3 * 128;
    sc.src[4] = b_emb;  sc.dst[4] = bembc; sc.n[4] = 128;
    sc.src[5] = bn1;    sc.dst[5] = bn1c; sc.n[5] = 128;
    sc.src[6] = bn2;    sc.dst[6] = bn2c; sc.n[6] = 64;
    sc.src[7] = be1;    sc.dst[7] = be1c; sc.n[7] = 128;
    sc.src[8] = be2;    sc.dst[8] = be2c; sc.n[8] = 3;
    cvt_small_kernel<<<2, 256, 0, stream>>>(sc, fflag);

    cvt_kernel<<<128, 256, 0, stream>>>(We1, We1c, 256 * 128, fflag);
    cvt_kernel<<<64, 256, 0, stream>>>(W_emb, Wembc, 128 * 128, fflag);

    // x -> bf16 into xw (free until first layer GEMM), then MFMA embedding.
    cvt_x_bf16_kernel<<<6250, 256, 0, stream>>>(x, xw, fflag);
    gemm_mfma_kernel<<<g64, 256, 0, stream>>>(
        xw, Wembc, bembc, h, NNODES, 1);

    // CSR build (once); Wembc consumed before scan1 writes 'off'.
    count_kernel<<<edge_blks, 256, 0, stream>>>(eidx, iflag, cnt);
    scan1_kernel<<<node_blks, 256, 0, stream>>>(cnt, off, bsum);
    scan2_kernel<<<1, 64, 0, stream>>>(bsum, node_blks);
    scan3_kernel<<<node_blks, 256, 0, stream>>>(off, bsum);
    zero_int_kernel<<<node_blks, 256, 0, stream>>>(cnt, NNODES);
    fill_kernel<<<edge_blks, 256, 0, stream>>>(eidx, iflag, off, cnt,
                                               csr_src, csr_dst, csr_eid, use_csr);

    // cnt region now dead -> stash node-MLP weights there.
    cvt_kernel<<<64, 256, 0, stream>>>(Wn1, Wn1c, 128 * 128, fflag);
    cvt_kernel<<<32, 256, 0, stream>>>(Wn2, Wn2c, 128 * 64, fflag);

    for (int l = 0; l < NLAYERS; l++) {
        cvt_layerW_kernel<<<64, 256, 0, stream>>>(gat_W, Wlc, l, fflag);
        gemm_mfma_kernel<<<g64, 256, 0, stream>>>(
            h, Wlc, (const float*)0, xw, NNODES, 0);
        alpha_kernel<<<(NNODES + 3) / 4, 256, 0, stream>>>(
            xw, asc + l * HDIM, adc + l * HDIM, alpha_s, alpha_d);
        aggregate_kernel<<<(NNODES + 3) / 4, 256, 0, stream>>>(
            xw, alpha_s, alpha_d, off, csr_src, gbc + l * HDIM, h);
    }

    // fused node MLP (t kept in LDS; xw untouched)
    node_mlp_kernel<<<g64, 256, 0, stream>>>(
        h, Wn1c, bn1c, Wn2c, bn2c, out, NNODES);

    // graph embedding (must precede edge_ab which overwrites h)
    gsum_kernel<<<NNODES / 200, 128, 0, stream>>>(h, gsum);
    gout_kernel<<<1, 128, 0, stream>>>(gsum, out);

    // fused edge A/B GEMMs: A -> xw, B -> h (in place)
    edge_ab_kernel<<<g64, 256, 0, stream>>>(
        h, We1c, be1c, xw, h, NNODES);
    edge_split_kernel<<<2048, 256, 0, stream>>>(
        xw, h, eidx, iflag, csr_src, csr_dst, csr_eid, use_csr,
        We2c, be2c, out + NODE_OUT_ELEMS);
}